// Round 6
// baseline (190.886 us; speedup 1.0000x reference)
//
#include <hip/hip_runtime.h>

typedef __attribute__((ext_vector_type(8))) short bf16x8;
typedef __attribute__((ext_vector_type(4))) float f32x4;
typedef __attribute__((ext_vector_type(8))) unsigned short u16x8;

constexpr int Bn = 16;
constexpr int Nn = 512;
constexpr int Fn = 64;
constexpr int Aout = 512;

static __device__ __forceinline__ unsigned short f2bf(float f) {
  union { float f; unsigned int u; } v; v.f = f;
  unsigned int r = v.u + 0x7fffu + ((v.u >> 16) & 1u);
  return (unsigned short)(r >> 16);
}
static __device__ __forceinline__ float bf2f(unsigned short u) {
  union { unsigned int u; float f; } v; v.u = ((unsigned int)u) << 16;
  return v.f;
}

// ---------------------------------------------------------------------------
// prep: [0,4096) adjs->bf16 x3 + bf16 sum; [4096,8192) hs_init->bf16;
//       [8192,8320) W_init -> W_init^T bf16.
// ---------------------------------------------------------------------------
__launch_bounds__(256)
__global__ void prep_kernel(const float4* __restrict__ a0,
                            const float4* __restrict__ a1,
                            const float4* __restrict__ a2,
                            const float4* __restrict__ hs,
                            ushort4* __restrict__ o0,
                            ushort4* __restrict__ o1,
                            ushort4* __restrict__ o2,
                            ushort4* __restrict__ osum,
                            ushort4* __restrict__ ohs,
                            const float* __restrict__ Wi,
                            unsigned short* __restrict__ WiT) {
  const int blk = blockIdx.x;
  if (blk < 4096) {
    size_t i = (size_t)blk * 256 + threadIdx.x;
    float4 x = a0[i], y = a1[i], z = a2[i];
    ushort4 p;
    p.x = f2bf(x.x); p.y = f2bf(x.y); p.z = f2bf(x.z); p.w = f2bf(x.w);
    o0[i] = p;
    p.x = f2bf(y.x); p.y = f2bf(y.y); p.z = f2bf(y.z); p.w = f2bf(y.w);
    o1[i] = p;
    p.x = f2bf(z.x); p.y = f2bf(z.y); p.z = f2bf(z.z); p.w = f2bf(z.w);
    o2[i] = p;
    p.x = f2bf(x.x + y.x + z.x); p.y = f2bf(x.y + y.y + z.y);
    p.z = f2bf(x.z + y.z + z.z); p.w = f2bf(x.w + y.w + z.w);
    osum[i] = p;
  } else if (blk < 8192) {
    size_t i = (size_t)(blk - 4096) * 256 + threadIdx.x;
    float4 x = hs[i];
    ushort4 p;
    p.x = f2bf(x.x); p.y = f2bf(x.y); p.z = f2bf(x.z); p.w = f2bf(x.w);
    ohs[i] = p;
  } else {
    int o = (blk - 8192) * 256 + threadIdx.x;  // 32768 = 64f x 512k
    int f = o >> 9, k = o & 511;
    WiT[o] = f2bf(Wi[k * Fn + f]);
  }
}

// ---------------------------------------------------------------------------
// LDS-staged MFMA GEMM (m97-style reg-staged pipeline).
// Block = (64-row tile, b, slot). K=512 in-block, 8 steps of BK=64.
// A: [16][512][512] bf16; X: [64][512] bf16 per b (or shared).
// Staging: contiguous 32B/lane global loads -> regs -> padded LDS [64][72].
// Compute: ds_read_b128 fragments -> mfma_f32_16x16x32_bf16.
// Epilogue: optional BN(n)+ReLU (h0), LDS transpose, contiguous stores to
// O[slot][b][64f][512n].
// ---------------------------------------------------------------------------
struct Slot2 {
  const unsigned short* A;
  const unsigned short* X;
  long long xbs;
};
struct G2 {
  Slot2 s[6];
  unsigned short* O;
  const float* mean; const float* var; const float* gamma; const float* beta;
};

__launch_bounds__(256, 4)
__global__ void gemm_stage_kernel(G2 g) {
  const int slot = blockIdx.z, b = blockIdx.y;
  const int R0 = blockIdx.x * 64;
  const int tid = threadIdx.x;
  const int w = tid >> 6, l = tid & 63;
  const int lr = l & 15, q = l >> 4;
  const Slot2 sl = g.s[slot];

  __shared__ __align__(16) unsigned short As[2][64][72];
  __shared__ __align__(16) unsigned short Xs[2][64][72];

  const int sr = tid >> 2;        // staging row 0..63
  const int sx = (tid & 3) * 16;  // elem offset within row (32B/lane)
  const unsigned short* Ab =
      sl.A + ((size_t)b << 18) + ((size_t)(R0 + sr) << 9) + sx;
  const unsigned short* Xb = sl.X + (size_t)b * sl.xbs + ((size_t)sr << 9) + sx;

  uint4 ra[4], rb[4];
  f32x4 acc[4] = {{0.f, 0.f, 0.f, 0.f},
                  {0.f, 0.f, 0.f, 0.f},
                  {0.f, 0.f, 0.f, 0.f},
                  {0.f, 0.f, 0.f, 0.f}};

#define ISSUE(R, T)                                                           \
  {                                                                           \
    const int k0_ = (T) * 64;                                                 \
    R[0] = *(const uint4*)(Ab + k0_);                                         \
    R[1] = *(const uint4*)(Ab + k0_ + 8);                                     \
    R[2] = *(const uint4*)(Xb + k0_);                                         \
    R[3] = *(const uint4*)(Xb + k0_ + 8);                                     \
  }
#define WRITE(R, BUF)                                                         \
  {                                                                           \
    *(uint4*)&As[BUF][sr][sx] = R[0];                                         \
    *(uint4*)&As[BUF][sr][sx + 8] = R[1];                                     \
    *(uint4*)&Xs[BUF][sr][sx] = R[2];                                         \
    *(uint4*)&Xs[BUF][sr][sx + 8] = R[3];                                     \
  }
#define COMPUTE(BUF)                                                          \
  {                                                                           \
    _Pragma("unroll") for (int h = 0; h < 2; ++h) {                           \
      bf16x8 af = *(const bf16x8*)&As[BUF][w * 16 + lr][q * 8 + h * 32];      \
      bf16x8 x0 = *(const bf16x8*)&Xs[BUF][lr][q * 8 + h * 32];               \
      bf16x8 x1 = *(const bf16x8*)&Xs[BUF][16 + lr][q * 8 + h * 32];          \
      bf16x8 x2 = *(const bf16x8*)&Xs[BUF][32 + lr][q * 8 + h * 32];          \
      bf16x8 x3 = *(const bf16x8*)&Xs[BUF][48 + lr][q * 8 + h * 32];          \
      acc[0] = __builtin_amdgcn_mfma_f32_16x16x32_bf16(af, x0, acc[0], 0, 0, 0); \
      acc[1] = __builtin_amdgcn_mfma_f32_16x16x32_bf16(af, x1, acc[1], 0, 0, 0); \
      acc[2] = __builtin_amdgcn_mfma_f32_16x16x32_bf16(af, x2, acc[2], 0, 0, 0); \
      acc[3] = __builtin_amdgcn_mfma_f32_16x16x32_bf16(af, x3, acc[3], 0, 0, 0); \
    }                                                                         \
  }

  ISSUE(ra, 0);
  for (int t = 0; t < 8; t += 2) {
    WRITE(ra, 0);
    if (t + 1 < 8) ISSUE(rb, t + 1);
    __syncthreads();
    COMPUTE(0);
    WRITE(rb, 1);
    if (t + 2 < 8) ISSUE(ra, t + 2);
    __syncthreads();
    COMPUTE(1);
  }
#undef ISSUE
#undef WRITE
#undef COMPUTE

  // epilogue: optional BN+ReLU over n, then LDS transpose (reuse As[0]) and
  // contiguous [f][n] stores.
  const bool hasbn = g.mean != nullptr;
  float sc[4], mu[4], bt[4];
  const int rbase = w * 16 + q * 4;
  if (hasbn) {
#pragma unroll
    for (int i = 0; i < 4; ++i) {
      int n = R0 + rbase + i;
      sc[i] = rsqrtf(g.var[n] + 1e-5f) * g.gamma[n];
      mu[i] = g.mean[n];
      bt[i] = g.beta[n];
    }
  }
#pragma unroll
  for (int c = 0; c < 4; ++c) {
    ushort4 wv;
#pragma unroll
    for (int i = 0; i < 4; ++i) {
      float v = acc[c][i];
      if (hasbn) v = fmaxf(fmaf(v - mu[i], sc[i], bt[i]), 0.f);
      ((unsigned short*)&wv)[i] = f2bf(v);
    }
    *(ushort4*)&As[0][c * 16 + lr][rbase] = wv;
  }
  __syncthreads();
  {
    const int fr = tid >> 2, c4 = tid & 3;
    unsigned short* O = g.O + (((size_t)slot * 16 + b) << 15) +
                        ((size_t)fr << 9) + R0 + c4 * 16;
    *(uint4*)O = *(const uint4*)&As[0][fr][c4 * 16];
    *(uint4*)(O + 8) = *(const uint4*)&As[0][fr][c4 * 16 + 8];
  }
}

// ---------------------------------------------------------------------------
// fuse: h_next = relu(BN(h@W3 + b + sum_z P_z@W_z)), P_z = sum of S partials.
// Optionally emits summed P_z (bf16). Block: (b, 32 n), 256 thr.
// ---------------------------------------------------------------------------
struct FArgs {
  const unsigned short* hT;
  const unsigned short* Pp;
  int S;
  const float *W3, *W0, *W1, *W2;
  const float *bias, *mean, *var, *gamma, *beta;
  unsigned short* outT;
  unsigned short* P0o;
  unsigned short* P1o;
  unsigned short* P2o;
};

__launch_bounds__(256)
__global__ void fuse_kernel(FArgs f) {
  const int b = blockIdx.y, nb = blockIdx.x;  // 16 blocks of 32 n
  const int t = threadIdx.x;
  __shared__ float sums[4][64][17];
  __shared__ __align__(16) unsigned short outH[64][40];
  __shared__ __align__(16) unsigned short outP[3][64][40];
  const int mat = t >> 6, k = t & 63;
  const int fo = t & 63, gq = t >> 6;
  const bool wantP = (f.P0o != nullptr);
  const float* Ws[4] = {f.W3, f.W0, f.W1, f.W2};

  for (int sub = 0; sub < 2; ++sub) {
    const int n0 = nb * 32 + sub * 16;
    float v[16];
    if (mat == 0) {
      const unsigned short* sp = f.hT + ((size_t)b << 15) + ((size_t)k << 9) + n0;
      u16x8 lo = *(const u16x8*)sp, hi = *(const u16x8*)(sp + 8);
#pragma unroll
      for (int e = 0; e < 8; ++e) {
        v[e] = bf2f((unsigned short)lo[e]);
        v[8 + e] = bf2f((unsigned short)hi[e]);
      }
    } else {
#pragma unroll
      for (int e = 0; e < 16; ++e) v[e] = 0.f;
      const int z = mat - 1;
      for (int sp = 0; sp < f.S; ++sp) {
        const unsigned short* p =
            f.Pp + ((((size_t)z * f.S + sp) * 16 + b) << 15) + ((size_t)k << 9) + n0;
        u16x8 lo = *(const u16x8*)p, hi = *(const u16x8*)(p + 8);
#pragma unroll
        for (int e = 0; e < 8; ++e) {
          v[e] += bf2f((unsigned short)lo[e]);
          v[8 + e] += bf2f((unsigned short)hi[e]);
        }
      }
    }
#pragma unroll
    for (int e = 0; e < 16; ++e) sums[mat][k][e] = v[e];
    if (wantP && mat >= 1) {
      u16x8 pw0, pw1;
#pragma unroll
      for (int e = 0; e < 8; ++e) {
        pw0[e] = f2bf(v[e]);
        pw1[e] = f2bf(v[8 + e]);
      }
      *(u16x8*)&outP[mat - 1][k][sub * 16] = pw0;
      *(u16x8*)&outP[mat - 1][k][sub * 16 + 8] = pw1;
    }
    __syncthreads();
    float acc[4] = {f.bias[fo], f.bias[fo], f.bias[fo], f.bias[fo]};
#pragma unroll
    for (int m2 = 0; m2 < 4; ++m2) {
      const float* __restrict__ W = Ws[m2];
#pragma unroll 8
      for (int k2 = 0; k2 < 64; ++k2) {
        float wv = W[k2 * 64 + fo];
#pragma unroll
        for (int i = 0; i < 4; ++i)
          acc[i] = fmaf(sums[m2][k2][gq * 4 + i], wv, acc[i]);
      }
    }
    ushort4 ov;
#pragma unroll
    for (int i = 0; i < 4; ++i) {
      int n = n0 + gq * 4 + i;
      float sc = rsqrtf(f.var[n] + 1e-5f) * f.gamma[n];
      float r = fmaf(acc[i] - f.mean[n], sc, f.beta[n]);
      ((unsigned short*)&ov)[i] = f2bf(fmaxf(r, 0.f));
    }
    *(ushort4*)&outH[fo][sub * 16 + gq * 4] = ov;
    __syncthreads();
  }

  const int fr = t >> 2, c4 = t & 3;
  const size_t gb = ((size_t)b << 15) + ((size_t)fr << 9) + nb * 32 + c4 * 8;
  *(u16x8*)(f.outT + gb) = *(const u16x8*)&outH[fr][c4 * 8];
  if (wantP) {
    *(u16x8*)(f.P0o + gb) = *(const u16x8*)&outP[0][fr][c4 * 8];
    *(u16x8*)(f.P1o + gb) = *(const u16x8*)&outP[1][fr][c4 * 8];
    *(u16x8*)(f.P2o + gb) = *(const u16x8*)&outP[2][fr][c4 * 8];
  }
}

// ---------------------------------------------------------------------------
// head: sum over n -> BN+ReLU -> FC(512) -> softmax. 1 block / batch.
// ---------------------------------------------------------------------------
__launch_bounds__(256)
__global__ void head_T_kernel(const unsigned short* __restrict__ h3T,
                              const float* __restrict__ gmean,
                              const float* __restrict__ gvar,
                              const float* __restrict__ ggamma,
                              const float* __restrict__ gbeta,
                              const float* __restrict__ fc_w,
                              const float* __restrict__ fc_b,
                              float* __restrict__ out) {
  const int b = blockIdx.x;
  const int t = threadIdx.x;
  __shared__ float part[256];
  __shared__ float gh[64];
  __shared__ float red[256];

  const int f = t >> 2, q = t & 3;
  const unsigned short* hp = h3T + ((size_t)b << 15) + ((size_t)f << 9) + q * 128;
  float s = 0.f;
#pragma unroll
  for (int j = 0; j < 16; ++j) {
    u16x8 v = *(const u16x8*)(hp + j * 8);
#pragma unroll
    for (int e = 0; e < 8; ++e) s += bf2f((unsigned short)v[e]);
  }
  part[t] = s;
  __syncthreads();
  if (t < 64) {
    float sum = part[t * 4] + part[t * 4 + 1] + part[t * 4 + 2] + part[t * 4 + 3];
    float sc = rsqrtf(gvar[t] + 1e-5f) * ggamma[t];
    float v = fmaf(sum - gmean[t], sc, gbeta[t]);
    gh[t] = v > 0.f ? v : 0.f;
  }
  __syncthreads();

  float lg[2];
#pragma unroll
  for (int rep = 0; rep < 2; ++rep) {
    const int a = t + rep * 256;
    const float* __restrict__ wv = fc_w + (size_t)a * Fn;
    float acc = fc_b[a];
#pragma unroll 8
    for (int kk = 0; kk < 64; ++kk) acc = fmaf(gh[kk], wv[kk], acc);
    lg[rep] = acc;
  }
  red[t] = fmaxf(lg[0], lg[1]);
  __syncthreads();
  for (int off = 128; off > 0; off >>= 1) {
    if (t < off) red[t] = fmaxf(red[t], red[t + off]);
    __syncthreads();
  }
  const float mx = red[0];
  __syncthreads();
  const float e0 = __expf(lg[0] - mx), e1 = __expf(lg[1] - mx);
  red[t] = e0 + e1;
  __syncthreads();
  for (int off = 128; off > 0; off >>= 1) {
    if (t < off) red[t] += red[t + off];
    __syncthreads();
  }
  const float inv = 1.f / red[0];
  out[(size_t)b * Aout + t] = e0 * inv;
  out[(size_t)b * Aout + t + 256] = e1 * inv;
}

// ---------------------------------------------------------------------------
extern "C" void kernel_launch(void* const* d_in, const int* in_sizes, int n_in,
                              void* d_out, int out_size, void* d_ws,
                              size_t ws_size, hipStream_t stream) {
  (void)in_sizes; (void)n_in; (void)out_size; (void)ws_size;
  const float* hs_init = (const float*)d_in[0];
  const float* adjs0 = (const float*)d_in[1];
  const float* adjs1 = (const float*)d_in[2];
  const float* adjs2 = (const float*)d_in[3];
  const float* W_init = (const float*)d_in[4];
  const float* W0 = (const float*)d_in[5];
  const float* W1 = (const float*)d_in[6];
  const float* W2 = (const float*)d_in[7];
  const float* W3 = (const float*)d_in[8];
  const float* bvec = (const float*)d_in[9];
  const float* fc1_w = (const float*)d_in[10];
  const float* fc1_b = (const float*)d_in[11];
  const float* bn_init_mean = (const float*)d_in[12];
  const float* bn_init_var = (const float*)d_in[13];
  const float* bn_init_gamma = (const float*)d_in[14];
  const float* bn_init_beta = (const float*)d_in[15];
  const float* bn_layer_mean = (const float*)d_in[16];
  const float* bn_layer_var = (const float*)d_in[17];
  const float* bn_layer_gamma = (const float*)d_in[18];
  const float* bn_layer_beta = (const float*)d_in[19];
  const float* bn_graph_mean = (const float*)d_in[20];
  const float* bn_graph_var = (const float*)d_in[21];
  const float* bn_graph_gamma = (const float*)d_in[22];
  const float* bn_graph_beta = (const float*)d_in[23];

  const size_t ADJ = (size_t)Bn * Nn * Nn;  // 4,194,304
  const size_t NF = (size_t)Bn * Fn * Nn;   // 524,288
  const size_t PLANE = (size_t)Bn * Fn * Nn;  // one partial set = 16 planes

  unsigned short* wsu = (unsigned short*)d_ws;
  unsigned short* adjsum = wsu;
  unsigned short* a0b = adjsum + ADJ;
  unsigned short* a1b = a0b + ADJ;
  unsigned short* a2b = a1b + ADJ;
  unsigned short* hsb = a2b + ADJ;
  unsigned short* WiT = hsb + ADJ;  // 32768
  unsigned short* h0T = WiT + 32768;
  unsigned short* h1T = h0T + NF;
  unsigned short* h2T = h1T + NF;
  unsigned short* h3T = h2T + NF;
  unsigned short* P0 = h3T + NF;
  unsigned short* P1 = P0 + NF;
  unsigned short* P2 = P1 + NF;
  unsigned short* partA = P2 + NF;        // 6 slot-planes
  unsigned short* partB = partA + 6 * PLANE;  // 6 slot-planes

  // 1) prep
  prep_kernel<<<dim3(8192 + 128), dim3(256), 0, stream>>>(
      (const float4*)adjs0, (const float4*)adjs1, (const float4*)adjs2,
      (const float4*)hs_init, (ushort4*)a0b, (ushort4*)a1b, (ushort4*)a2b,
      (ushort4*)adjsum, (ushort4*)hsb, W_init, WiT);

  // 2) h0 = relu(BN_init(hs @ Wi))  (K=512 in-block, BN fused)
  {
    G2 a = {};
    a.s[0] = {hsb, WiT, 0};
    a.O = h0T;  // slot 0, plane layout == [b][f][n]
    a.mean = bn_init_mean; a.var = bn_init_var;
    a.gamma = bn_init_gamma; a.beta = bn_init_beta;
    gemm_stage_kernel<<<dim3(8, Bn, 1), dim3(256), 0, stream>>>(a);
  }

  const unsigned short* ab[3] = {a0b, a1b, a2b};

  // 3) L0: partA[z] = a_z @ h0  (this IS P_z[0])
  {
    G2 a = {};
    for (int z = 0; z < 3; ++z) a.s[z] = {ab[z], h0T, 32768};
    a.O = partA;
    gemm_stage_kernel<<<dim3(8, Bn, 3), dim3(256), 0, stream>>>(a);
  }
  // 4) fuse L0 (S=1) -> h1 (no P emit; L1 reads partA planes directly)
  {
    FArgs fa = {};
    fa.hT = h0T; fa.Pp = partA; fa.S = 1;
    fa.W3 = W3; fa.W0 = W0; fa.W1 = W1; fa.W2 = W2;
    fa.bias = bvec; fa.mean = bn_layer_mean; fa.var = bn_layer_var;
    fa.gamma = bn_layer_gamma; fa.beta = bn_layer_beta;
    fa.outT = h1T; fa.P0o = nullptr; fa.P1o = nullptr; fa.P2o = nullptr;
    fuse_kernel<<<dim3(16, Bn), dim3(256), 0, stream>>>(fa);
  }

  // 5) L1: partB[z*2] = a_z @ h1 ; partB[z*2+1] = adjsum @ P_z[0]
  {
    G2 a = {};
    for (int z = 0; z < 3; ++z) {
      a.s[z * 2] = {ab[z], h1T, 32768};
      a.s[z * 2 + 1] = {adjsum, partA + (((size_t)z * 16) << 15), 32768};
    }
    a.O = partB;
    gemm_stage_kernel<<<dim3(8, Bn, 6), dim3(256), 0, stream>>>(a);
  }
  // 6) fuse L1 (S=2) -> h2, emits summed P_z[1]
  {
    FArgs fa = {};
    fa.hT = h1T; fa.Pp = partB; fa.S = 2;
    fa.W3 = W3 + 4096; fa.W0 = W0 + 4096; fa.W1 = W1 + 4096; fa.W2 = W2 + 4096;
    fa.bias = bvec + 64; fa.mean = bn_layer_mean + 512;
    fa.var = bn_layer_var + 512; fa.gamma = bn_layer_gamma + 512;
    fa.beta = bn_layer_beta + 512;
    fa.outT = h2T; fa.P0o = P0; fa.P1o = P1; fa.P2o = P2;
    fuse_kernel<<<dim3(16, Bn), dim3(256), 0, stream>>>(fa);
  }

  // 7) L2: partA[z*2] = a_z @ h2 ; partA[z*2+1] = adjsum @ P_z[1]
  {
    G2 a = {};
    const unsigned short* Ps[3] = {P0, P1, P2};
    for (int z = 0; z < 3; ++z) {
      a.s[z * 2] = {ab[z], h2T, 32768};
      a.s[z * 2 + 1] = {adjsum, Ps[z], 32768};
    }
    a.O = partA;
    gemm_stage_kernel<<<dim3(8, Bn, 6), dim3(256), 0, stream>>>(a);
  }
  // 8) fuse L2 (S=2) -> h3
  {
    FArgs fa = {};
    fa.hT = h2T; fa.Pp = partA; fa.S = 2;
    fa.W3 = W3 + 8192; fa.W0 = W0 + 8192; fa.W1 = W1 + 8192; fa.W2 = W2 + 8192;
    fa.bias = bvec + 128; fa.mean = bn_layer_mean + 1024;
    fa.var = bn_layer_var + 1024; fa.gamma = bn_layer_gamma + 1024;
    fa.beta = bn_layer_beta + 1024;
    fa.outT = h3T; fa.P0o = nullptr; fa.P1o = nullptr; fa.P2o = nullptr;
    fuse_kernel<<<dim3(16, Bn), dim3(256), 0, stream>>>(fa);
  }

  // 9) head
  head_T_kernel<<<dim3(Bn), dim3(256), 0, stream>>>(
      h3T, bn_graph_mean, bn_graph_var, bn_graph_gamma, bn_graph_beta, fc1_w,
      fc1_b, (float*)d_out);
}

// Round 7
// 146.442 us; speedup vs baseline: 1.3035x; 1.3035x over previous
//
#include <hip/hip_runtime.h>

typedef __attribute__((ext_vector_type(8))) short bf16x8;
typedef __attribute__((ext_vector_type(4))) float f32x4;
typedef __attribute__((ext_vector_type(8))) unsigned short u16x8;

constexpr int Bn = 16;
constexpr int Nn = 512;
constexpr int Fn = 64;
constexpr int Aout = 512;

static __device__ __forceinline__ unsigned short f2bf(float f) {
  union { float f; unsigned int u; } v; v.f = f;
  unsigned int r = v.u + 0x7fffu + ((v.u >> 16) & 1u);
  return (unsigned short)(r >> 16);
}
static __device__ __forceinline__ float bf2f(unsigned short u) {
  union { unsigned int u; float f; } v; v.u = ((unsigned int)u) << 16;
  return v.f;
}
static __device__ __forceinline__ unsigned int pk2(float a, float b) {
  union { float f; unsigned int u; } ua, ub; ua.f = a; ub.f = b;
  return ((ua.u + 0x8000u) >> 16) | ((ub.u + 0x8000u) & 0xFFFF0000u);
}

// A-fragment permutation (A-operand of mfma_f32_16x16x32_bf16):
//   APerm(n,k) = ((n>>4)*16 + (k>>5))<<9 | ((n&15) + 16*((k>>3)&3))<<3 | (k&7)
// B-fragment permutation (X-operand), col f, contraction n:
//   BPerm(f,n) = ((f>>4)*16 + (n>>5))<<9 | ((f&15) + 16*((n>>3)&3))<<3 | (n&7)

// ---------------------------------------------------------------------------
// prep: adjacency fp32 -> bf16 A-perm (a0p,a1p,a2p + sum); hs_init -> A-perm;
// W_init -> B-perm.
// ---------------------------------------------------------------------------
__launch_bounds__(256)
__global__ void prep_kernel(const float* __restrict__ a0,
                            const float* __restrict__ a1,
                            const float* __restrict__ a2,
                            const float* __restrict__ hs,
                            unsigned short* __restrict__ a0p,
                            unsigned short* __restrict__ a1p,
                            unsigned short* __restrict__ a2p,
                            unsigned short* __restrict__ asump,
                            unsigned short* __restrict__ hsp,
                            const float* __restrict__ Wi,
                            unsigned short* __restrict__ Wp) {
  const int blk = blockIdx.x;
  if (blk < 4096) {
    const bool do_hs = blk >= 2048;
    const int idx = (do_hs ? blk - 2048 : blk) * 256 + threadIdx.x;  // [0,524288)
    const int b = idx >> 15, n = (idx >> 6) & 511, o = idx & 63;
    const int k0 = o * 8;
    const size_t src = ((size_t)b << 18) + ((size_t)n << 9) + k0;
    const size_t dst = ((size_t)b << 18) +
                       ((size_t)((n >> 4) * 16 + (k0 >> 5)) << 9) +
                       (((n & 15) + 16 * ((k0 >> 3) & 3)) << 3);
    if (do_hs) {
      float4 lo = *(const float4*)(hs + src);
      float4 hi = *(const float4*)(hs + src + 4);
      uint4 w;
      w.x = pk2(lo.x, lo.y); w.y = pk2(lo.z, lo.w);
      w.z = pk2(hi.x, hi.y); w.w = pk2(hi.z, hi.w);
      *(uint4*)(hsp + dst) = w;
    } else {
      float4 x0 = *(const float4*)(a0 + src);
      float4 x1 = *(const float4*)(a0 + src + 4);
      float4 y0 = *(const float4*)(a1 + src);
      float4 y1 = *(const float4*)(a1 + src + 4);
      float4 z0 = *(const float4*)(a2 + src);
      float4 z1 = *(const float4*)(a2 + src + 4);
      uint4 w;
      w.x = pk2(x0.x, x0.y); w.y = pk2(x0.z, x0.w);
      w.z = pk2(x1.x, x1.y); w.w = pk2(x1.z, x1.w);
      *(uint4*)(a0p + dst) = w;
      w.x = pk2(y0.x, y0.y); w.y = pk2(y0.z, y0.w);
      w.z = pk2(y1.x, y1.y); w.w = pk2(y1.z, y1.w);
      *(uint4*)(a1p + dst) = w;
      w.x = pk2(z0.x, z0.y); w.y = pk2(z0.z, z0.w);
      w.z = pk2(z1.x, z1.y); w.w = pk2(z1.z, z1.w);
      *(uint4*)(a2p + dst) = w;
      w.x = pk2(x0.x + y0.x + z0.x, x0.y + y0.y + z0.y);
      w.y = pk2(x0.z + y0.z + z0.z, x0.w + y0.w + z0.w);
      w.z = pk2(x1.x + y1.x + z1.x, x1.y + y1.y + z1.y);
      w.w = pk2(x1.z + y1.z + z1.z, x1.w + y1.w + z1.w);
      *(uint4*)(asump + dst) = w;
    }
  } else {
    const int idx = (blk - 4096) * 256 + threadIdx.x;  // [0,4096)
    const int f = idx >> 6, o = idx & 63;
    const int k0 = o * 8;
    const size_t dst = ((size_t)((f >> 4) * 16 + (k0 >> 5)) << 9) +
                       (((f & 15) + 16 * ((k0 >> 3) & 3)) << 3);
    unsigned short w[8];
#pragma unroll
    for (int j = 0; j < 8; ++j) w[j] = f2bf(Wi[(size_t)(k0 + j) * Fn + f]);
    *(uint4*)(Wp + dst) = *(const uint4*)w;
  }
}

// ---------------------------------------------------------------------------
// Fragment-direct MFMA GEMM: zero LDS / zero barriers in K-loop.
// Block = (64 A-rows, b, slot), K=512 = 16 fragment steps, 2-deep reg
// prefetch. A: A-perm bf16 [b][512][512]; X: B-perm bf16 [64][512] per b.
// Epilogue: optional BN(row n)+ReLU, LDS transpose, B-perm output
// (plane (slot*16+b), so outputs are directly consumable as next X).
// ---------------------------------------------------------------------------
struct Slot3 { const unsigned short* A; const unsigned short* X; long long xbs; };
struct G3 {
  Slot3 s[6];
  unsigned short* O;
  const float* mean; const float* var; const float* gamma; const float* beta;
};

__launch_bounds__(256, 4)
__global__ void gemm_frag_kernel(G3 g) {
  const int slot = blockIdx.z, b = blockIdx.y;
  const int R0 = blockIdx.x * 64;
  const int tid = threadIdx.x;
  const int w = tid >> 6, l = tid & 63;
  const Slot3 sl = g.s[slot];

  const unsigned short* Af = sl.A + ((size_t)b << 18) +
                             ((size_t)((blockIdx.x * 4 + w) * 16) << 9) + l * 8;
  const unsigned short* Xf = sl.X + (size_t)b * sl.xbs + l * 8;

  f32x4 acc[4] = {{0.f, 0.f, 0.f, 0.f},
                  {0.f, 0.f, 0.f, 0.f},
                  {0.f, 0.f, 0.f, 0.f},
                  {0.f, 0.f, 0.f, 0.f}};

  bf16x8 ac = *(const bf16x8*)Af;
  bf16x8 x0 = *(const bf16x8*)Xf;
  bf16x8 x1 = *(const bf16x8*)(Xf + (16 << 9));
  bf16x8 x2 = *(const bf16x8*)(Xf + (32 << 9));
  bf16x8 x3 = *(const bf16x8*)(Xf + (48 << 9));

#pragma unroll
  for (int t = 0; t < 16; ++t) {
    bf16x8 an, n0, n1, n2, n3;
    if (t < 15) {
      const int d = (t + 1) * 512;
      an = *(const bf16x8*)(Af + d);
      n0 = *(const bf16x8*)(Xf + d);
      n1 = *(const bf16x8*)(Xf + (16 << 9) + d);
      n2 = *(const bf16x8*)(Xf + (32 << 9) + d);
      n3 = *(const bf16x8*)(Xf + (48 << 9) + d);
    }
    acc[0] = __builtin_amdgcn_mfma_f32_16x16x32_bf16(ac, x0, acc[0], 0, 0, 0);
    acc[1] = __builtin_amdgcn_mfma_f32_16x16x32_bf16(ac, x1, acc[1], 0, 0, 0);
    acc[2] = __builtin_amdgcn_mfma_f32_16x16x32_bf16(ac, x2, acc[2], 0, 0, 0);
    acc[3] = __builtin_amdgcn_mfma_f32_16x16x32_bf16(ac, x3, acc[3], 0, 0, 0);
    if (t < 15) { ac = an; x0 = n0; x1 = n1; x2 = n2; x3 = n3; }
  }

  // epilogue: optional BN+ReLU over rows n, LDS transpose, B-perm stores
  __shared__ __align__(16) unsigned short T[64][72];
  const int lr = l & 15, q = l >> 4;
  const int rbase = w * 16 + q * 4;
  const bool hasbn = g.mean != nullptr;
  float sc[4], mu[4], bt[4];
  if (hasbn) {
#pragma unroll
    for (int i = 0; i < 4; ++i) {
      int n = R0 + rbase + i;
      sc[i] = rsqrtf(g.var[n] + 1e-5f) * g.gamma[n];
      mu[i] = g.mean[n];
      bt[i] = g.beta[n];
    }
  }
#pragma unroll
  for (int c = 0; c < 4; ++c) {
#pragma unroll
    for (int i = 0; i < 4; ++i) {
      float v = acc[c][i];
      if (hasbn) v = fmaxf(fmaf(v - mu[i], sc[i], bt[i]), 0.f);
      T[c * 16 + lr][rbase + i] = f2bf(v);
    }
  }
  __syncthreads();
  {
    const int f = tid >> 2, oc = tid & 3;
    unsigned short* Ob = g.O + (((size_t)slot * 16 + b) << 15);
#pragma unroll
    for (int p = 0; p < 2; ++p) {
      const int nl = oc * 8 + p * 32;  // local n octet base
      const int nn = R0 + nl;
      const size_t dst = ((size_t)((f >> 4) * 16 + (nn >> 5)) << 9) +
                         (((f & 15) + 16 * ((nl >> 3) & 3)) << 3);
      *(uint4*)(Ob + dst) = *(const uint4*)&T[f][nl];
    }
  }
}

// ---------------------------------------------------------------------------
// fuse: h_next = relu(BN(h@W3 + b + sum_z P_z@W_z)), P_z = sum of S partials.
// All bf16 tensor I/O in B-perm layout. Optionally emits summed P_z.
// Block: (b, 32 n), 256 thr.
// ---------------------------------------------------------------------------
struct FArgs {
  const unsigned short* hT;
  const unsigned short* Pp;
  int S;
  const float *W3, *W0, *W1, *W2;
  const float *bias, *mean, *var, *gamma, *beta;
  unsigned short* outT;
  unsigned short* P0o;
  unsigned short* P1o;
  unsigned short* P2o;
};

__launch_bounds__(256)
__global__ void fuse_kernel(FArgs f) {
  const int b = blockIdx.y, nb = blockIdx.x;  // 16 blocks of 32 n
  const int t = threadIdx.x;
  __shared__ float sums[4][64][17];
  __shared__ __align__(16) unsigned short outH[64][40];
  __shared__ __align__(16) unsigned short outP[3][64][40];
  const int mat = t >> 6, k = t & 63;
  const int fo = t & 63, gq = t >> 6;
  const bool wantP = (f.P0o != nullptr);
  const float* Ws[4] = {f.W3, f.W0, f.W1, f.W2};

  for (int sub = 0; sub < 2; ++sub) {
    const int n0 = nb * 32 + sub * 16;
    // B-perm read of h / partial planes at (col k, n window [n0,n0+16))
    const size_t fb = ((size_t)((k >> 4) * 16 + (n0 >> 5)) << 9) +
                      (((k & 15) + 16 * ((n0 >> 3) & 3)) << 3);
    float v[16];
    if (mat == 0) {
      const unsigned short* sp = f.hT + ((size_t)b << 15) + fb;
      u16x8 lo = *(const u16x8*)sp, hi = *(const u16x8*)(sp + 128);
#pragma unroll
      for (int e = 0; e < 8; ++e) {
        v[e] = bf2f((unsigned short)lo[e]);
        v[8 + e] = bf2f((unsigned short)hi[e]);
      }
    } else {
#pragma unroll
      for (int e = 0; e < 16; ++e) v[e] = 0.f;
      const int z = mat - 1;
      for (int sp2 = 0; sp2 < f.S; ++sp2) {
        const unsigned short* p =
            f.Pp + ((((size_t)z * f.S + sp2) * 16 + b) << 15) + fb;
        u16x8 lo = *(const u16x8*)p, hi = *(const u16x8*)(p + 128);
#pragma unroll
        for (int e = 0; e < 8; ++e) {
          v[e] += bf2f((unsigned short)lo[e]);
          v[8 + e] += bf2f((unsigned short)hi[e]);
        }
      }
    }
#pragma unroll
    for (int e = 0; e < 16; ++e) sums[mat][k][e] = v[e];
    if (wantP && mat >= 1) {
      u16x8 pw0, pw1;
#pragma unroll
      for (int e = 0; e < 8; ++e) {
        pw0[e] = f2bf(v[e]);
        pw1[e] = f2bf(v[8 + e]);
      }
      *(u16x8*)&outP[mat - 1][k][sub * 16] = pw0;
      *(u16x8*)&outP[mat - 1][k][sub * 16 + 8] = pw1;
    }
    __syncthreads();
    float acc[4] = {f.bias[fo], f.bias[fo], f.bias[fo], f.bias[fo]};
#pragma unroll
    for (int m2 = 0; m2 < 4; ++m2) {
      const float* __restrict__ W = Ws[m2];
#pragma unroll 8
      for (int k2 = 0; k2 < 64; ++k2) {
        float wv = W[k2 * 64 + fo];
#pragma unroll
        for (int i = 0; i < 4; ++i)
          acc[i] = fmaf(sums[m2][k2][gq * 4 + i], wv, acc[i]);
      }
    }
    ushort4 ov;
#pragma unroll
    for (int i = 0; i < 4; ++i) {
      int n = n0 + gq * 4 + i;
      float sc = rsqrtf(f.var[n] + 1e-5f) * f.gamma[n];
      float r = fmaf(acc[i] - f.mean[n], sc, f.beta[n]);
      ((unsigned short*)&ov)[i] = f2bf(fmaxf(r, 0.f));
    }
    *(ushort4*)&outH[fo][sub * 16 + gq * 4] = ov;
    __syncthreads();
  }

  // B-perm stores: thread (fr, oc) handles one 8-n octet at n0w
  const int fr = t >> 2, oc = t & 3;
  const int n0w = nb * 32 + oc * 8;
  const size_t dst = ((size_t)b << 15) +
                     ((size_t)((fr >> 4) * 16 + (n0w >> 5)) << 9) +
                     (((fr & 15) + 16 * ((n0w >> 3) & 3)) << 3);
  *(u16x8*)(f.outT + dst) = *(const u16x8*)&outH[fr][oc * 8];
  if (wantP) {
    *(u16x8*)(f.P0o + dst) = *(const u16x8*)&outP[0][fr][oc * 8];
    *(u16x8*)(f.P1o + dst) = *(const u16x8*)&outP[1][fr][oc * 8];
    *(u16x8*)(f.P2o + dst) = *(const u16x8*)&outP[2][fr][oc * 8];
  }
}

// ---------------------------------------------------------------------------
// head: sum over n (B-perm h3) -> BN+ReLU -> FC(512) -> softmax. block per b.
// ---------------------------------------------------------------------------
__launch_bounds__(256)
__global__ void head_kernel(const unsigned short* __restrict__ h3p,
                            const float* __restrict__ gmean,
                            const float* __restrict__ gvar,
                            const float* __restrict__ ggamma,
                            const float* __restrict__ gbeta,
                            const float* __restrict__ fc_w,
                            const float* __restrict__ fc_b,
                            float* __restrict__ out) {
  const int b = blockIdx.x;
  const int t = threadIdx.x;
  __shared__ float part[256];
  __shared__ float gh[64];
  __shared__ float red[256];

  const int f = t >> 2, q = t & 3;
  const unsigned short* hp = h3p + ((size_t)b << 15);
  float s = 0.f;
#pragma unroll
  for (int m = 0; m < 16; ++m) {
    const int n = q * 128 + m * 8;
    const size_t off = ((size_t)((f >> 4) * 16 + (n >> 5)) << 9) +
                       (((f & 15) + 16 * ((n >> 3) & 3)) << 3);
    u16x8 v = *(const u16x8*)(hp + off);
#pragma unroll
    for (int e = 0; e < 8; ++e) s += bf2f((unsigned short)v[e]);
  }
  part[t] = s;
  __syncthreads();
  if (t < 64) {
    float sum = part[t * 4] + part[t * 4 + 1] + part[t * 4 + 2] + part[t * 4 + 3];
    float sc = rsqrtf(gvar[t] + 1e-5f) * ggamma[t];
    float v = fmaf(sum - gmean[t], sc, gbeta[t]);
    gh[t] = v > 0.f ? v : 0.f;
  }
  __syncthreads();

  float lg[2];
#pragma unroll
  for (int rep = 0; rep < 2; ++rep) {
    const int a = t + rep * 256;
    const float* __restrict__ wv = fc_w + (size_t)a * Fn;
    float acc = fc_b[a];
#pragma unroll 8
    for (int kk = 0; kk < 64; ++kk) acc = fmaf(gh[kk], wv[kk], acc);
    lg[rep] = acc;
  }
  red[t] = fmaxf(lg[0], lg[1]);
  __syncthreads();
  for (int off = 128; off > 0; off >>= 1) {
    if (t < off) red[t] = fmaxf(red[t], red[t + off]);
    __syncthreads();
  }
  const float mx = red[0];
  __syncthreads();
  const float e0 = __expf(lg[0] - mx), e1 = __expf(lg[1] - mx);
  red[t] = e0 + e1;
  __syncthreads();
  for (int off = 128; off > 0; off >>= 1) {
    if (t < off) red[t] += red[t + off];
    __syncthreads();
  }
  const float inv = 1.f / red[0];
  out[(size_t)b * Aout + t] = e0 * inv;
  out[(size_t)b * Aout + t + 256] = e1 * inv;
}

// ---------------------------------------------------------------------------
extern "C" void kernel_launch(void* const* d_in, const int* in_sizes, int n_in,
                              void* d_out, int out_size, void* d_ws,
                              size_t ws_size, hipStream_t stream) {
  (void)in_sizes; (void)n_in; (void)out_size; (void)ws_size;
  const float* hs_init = (const float*)d_in[0];
  const float* adjs0 = (const float*)d_in[1];
  const float* adjs1 = (const float*)d_in[2];
  const float* adjs2 = (const float*)d_in[3];
  const float* W_init = (const float*)d_in[4];
  const float* W0 = (const float*)d_in[5];
  const float* W1 = (const float*)d_in[6];
  const float* W2 = (const float*)d_in[7];
  const float* W3 = (const float*)d_in[8];
  const float* bvec = (const float*)d_in[9];
  const float* fc1_w = (const float*)d_in[10];
  const float* fc1_b = (const float*)d_in[11];
  const float* bn_init_mean = (const float*)d_in[12];
  const float* bn_init_var = (const float*)d_in[13];
  const float* bn_init_gamma = (const float*)d_in[14];
  const float* bn_init_beta = (const float*)d_in[15];
  const float* bn_layer_mean = (const float*)d_in[16];
  const float* bn_layer_var = (const float*)d_in[17];
  const float* bn_layer_gamma = (const float*)d_in[18];
  const float* bn_layer_beta = (const float*)d_in[19];
  const float* bn_graph_mean = (const float*)d_in[20];
  const float* bn_graph_var = (const float*)d_in[21];
  const float* bn_graph_gamma = (const float*)d_in[22];
  const float* bn_graph_beta = (const float*)d_in[23];

  const size_t ADJ = (size_t)Bn * Nn * Nn;  // 4,194,304
  const size_t NF = (size_t)Bn * Fn * Nn;   // 524,288

  unsigned short* wsu = (unsigned short*)d_ws;
  unsigned short* a0p = wsu;
  unsigned short* a1p = a0p + ADJ;
  unsigned short* a2p = a1p + ADJ;
  unsigned short* asump = a2p + ADJ;
  unsigned short* hsp = asump + ADJ;
  unsigned short* Wp = hsp + ADJ;   // 32768
  unsigned short* h0p = Wp + 32768;
  unsigned short* h1p = h0p + NF;
  unsigned short* h2p = h1p + NF;
  unsigned short* h3p = h2p + NF;
  unsigned short* P0p = h3p + NF;
  unsigned short* P1p = P0p + NF;
  unsigned short* P2p = P1p + NF;
  unsigned short* partA = P2p + NF;        // 6 planes
  unsigned short* partB = partA + 6 * NF;  // 6 planes

  // 1) prep
  prep_kernel<<<dim3(4096 + 16), dim3(256), 0, stream>>>(
      adjs0, adjs1, adjs2, hs_init, a0p, a1p, a2p, asump, hsp, W_init, Wp);

  // 2) h0 = relu(BN_init(hs @ Wi))  -> h0p (B-perm)
  {
    G3 a = {};
    a.s[0] = {hsp, Wp, 0};
    a.O = h0p;  // plane (0,b) == [b]<<15
    a.mean = bn_init_mean; a.var = bn_init_var;
    a.gamma = bn_init_gamma; a.beta = bn_init_beta;
    gemm_frag_kernel<<<dim3(8, Bn, 1), dim3(256), 0, stream>>>(a);
  }

  const unsigned short* ap[3] = {a0p, a1p, a2p};
  const long long nfb = 32768;

  // 3) L0: partA[z] = a_z @ h0  (== P_z[0])
  {
    G3 a = {};
    for (int z = 0; z < 3; ++z) a.s[z] = {ap[z], h0p, nfb};
    a.O = partA;
    gemm_frag_kernel<<<dim3(8, Bn, 3), dim3(256), 0, stream>>>(a);
  }
  // 4) fuse L0 (S=1) -> h1p
  {
    FArgs fa = {};
    fa.hT = h0p; fa.Pp = partA; fa.S = 1;
    fa.W3 = W3; fa.W0 = W0; fa.W1 = W1; fa.W2 = W2;
    fa.bias = bvec; fa.mean = bn_layer_mean; fa.var = bn_layer_var;
    fa.gamma = bn_layer_gamma; fa.beta = bn_layer_beta;
    fa.outT = h1p; fa.P0o = nullptr; fa.P1o = nullptr; fa.P2o = nullptr;
    fuse_kernel<<<dim3(16, Bn), dim3(256), 0, stream>>>(fa);
  }

  // 5) L1: partB[z*2] = a_z @ h1 ; partB[z*2+1] = asum @ P_z[0] (partA plane z)
  {
    G3 a = {};
    for (int z = 0; z < 3; ++z) {
      a.s[z * 2] = {ap[z], h1p, nfb};
      a.s[z * 2 + 1] = {asump, partA + (((size_t)z * 16) << 15), nfb};
    }
    a.O = partB;
    gemm_frag_kernel<<<dim3(8, Bn, 6), dim3(256), 0, stream>>>(a);
  }
  // 6) fuse L1 (S=2) -> h2p + P_zp
  {
    FArgs fa = {};
    fa.hT = h1p; fa.Pp = partB; fa.S = 2;
    fa.W3 = W3 + 4096; fa.W0 = W0 + 4096; fa.W1 = W1 + 4096; fa.W2 = W2 + 4096;
    fa.bias = bvec + 64; fa.mean = bn_layer_mean + 512;
    fa.var = bn_layer_var + 512; fa.gamma = bn_layer_gamma + 512;
    fa.beta = bn_layer_beta + 512;
    fa.outT = h2p; fa.P0o = P0p; fa.P1o = P1p; fa.P2o = P2p;
    fuse_kernel<<<dim3(16, Bn), dim3(256), 0, stream>>>(fa);
  }

  // 7) L2: partA[z*2] = a_z @ h2 ; partA[z*2+1] = asum @ P_z[1]
  {
    G3 a = {};
    const unsigned short* Ps[3] = {P0p, P1p, P2p};
    for (int z = 0; z < 3; ++z) {
      a.s[z * 2] = {ap[z], h2p, nfb};
      a.s[z * 2 + 1] = {asump, Ps[z], nfb};
    }
    a.O = partA;
    gemm_frag_kernel<<<dim3(8, Bn, 6), dim3(256), 0, stream>>>(a);
  }
  // 8) fuse L2 (S=2) -> h3p
  {
    FArgs fa = {};
    fa.hT = h2p; fa.Pp = partA; fa.S = 2;
    fa.W3 = W3 + 8192; fa.W0 = W0 + 8192; fa.W1 = W1 + 8192; fa.W2 = W2 + 8192;
    fa.bias = bvec + 128; fa.mean = bn_layer_mean + 1024;
    fa.var = bn_layer_var + 1024; fa.gamma = bn_layer_gamma + 1024;
    fa.beta = bn_layer_beta + 1024;
    fa.outT = h3p; fa.P0o = nullptr; fa.P1o = nullptr; fa.P2o = nullptr;
    fuse_kernel<<<dim3(16, Bn), dim3(256), 0, stream>>>(fa);
  }

  // 9) head
  head_kernel<<<dim3(Bn), dim3(256), 0, stream>>>(
      h3p, bn_graph_mean, bn_graph_var, bn_graph_gamma, bn_graph_beta, fc1_w,
      fc1_b, (float*)d_out);
}

// Round 8
// 144.831 us; speedup vs baseline: 1.3180x; 1.0111x over previous
//
#include <hip/hip_runtime.h>

typedef __attribute__((ext_vector_type(8))) short bf16x8;
typedef __attribute__((ext_vector_type(4))) float f32x4;
typedef __attribute__((ext_vector_type(8))) unsigned short u16x8;

constexpr int Bn = 16;
constexpr int Nn = 512;
constexpr int Fn = 64;
constexpr int Aout = 512;

static __device__ __forceinline__ unsigned short f2bf(float f) {
  union { float f; unsigned int u; } v; v.f = f;
  unsigned int r = v.u + 0x7fffu + ((v.u >> 16) & 1u);
  return (unsigned short)(r >> 16);
}
static __device__ __forceinline__ float bf2f(unsigned short u) {
  union { unsigned int u; float f; } v; v.u = ((unsigned int)u) << 16;
  return v.f;
}
static __device__ __forceinline__ unsigned int pk2(float a, float b) {
  union { float f; unsigned int u; } ua, ub; ua.f = a; ub.f = b;
  return ((ua.u + 0x8000u) >> 16) | ((ub.u + 0x8000u) & 0xFFFF0000u);
}

// B-fragment permutation (X-operand of mfma_f32_16x16x32_bf16), col f,
// contraction n: BPerm(f,n) = ((f>>4)*16+(n>>5))<<9 | ((f&15)+16*((n>>3)&3))<<3 | (n&7)

// ---------------------------------------------------------------------------
// prep: pure streaming converts, all coalesced 16B stores.
// [0,2048): adjs0/1/2 -> linear bf16 + bf16 sum (8 elems/thread)
// [2048,4096): hs_init -> linear bf16
// [4096,4112): W_init -> B-perm bf16
// ---------------------------------------------------------------------------
__launch_bounds__(256)
__global__ void prep_kernel(const float* __restrict__ a0,
                            const float* __restrict__ a1,
                            const float* __restrict__ a2,
                            const float* __restrict__ hs,
                            unsigned short* __restrict__ o0,
                            unsigned short* __restrict__ o1,
                            unsigned short* __restrict__ o2,
                            unsigned short* __restrict__ osum,
                            unsigned short* __restrict__ ohs,
                            const float* __restrict__ Wi,
                            unsigned short* __restrict__ Wp) {
  const int blk = blockIdx.x;
  if (blk < 2048) {
    const size_t i = ((size_t)blk * 256 + threadIdx.x) * 8;
    float4 xl = *(const float4*)(a0 + i), xh = *(const float4*)(a0 + i + 4);
    float4 yl = *(const float4*)(a1 + i), yh = *(const float4*)(a1 + i + 4);
    float4 zl = *(const float4*)(a2 + i), zh = *(const float4*)(a2 + i + 4);
    uint4 w;
    w.x = pk2(xl.x, xl.y); w.y = pk2(xl.z, xl.w);
    w.z = pk2(xh.x, xh.y); w.w = pk2(xh.z, xh.w);
    *(uint4*)(o0 + i) = w;
    w.x = pk2(yl.x, yl.y); w.y = pk2(yl.z, yl.w);
    w.z = pk2(yh.x, yh.y); w.w = pk2(yh.z, yh.w);
    *(uint4*)(o1 + i) = w;
    w.x = pk2(zl.x, zl.y); w.y = pk2(zl.z, zl.w);
    w.z = pk2(zh.x, zh.y); w.w = pk2(zh.z, zh.w);
    *(uint4*)(o2 + i) = w;
    w.x = pk2(xl.x + yl.x + zl.x, xl.y + yl.y + zl.y);
    w.y = pk2(xl.z + yl.z + zl.z, xl.w + yl.w + zl.w);
    w.z = pk2(xh.x + yh.x + zh.x, xh.y + yh.y + zh.y);
    w.w = pk2(xh.z + yh.z + zh.z, xh.w + yh.w + zh.w);
    *(uint4*)(osum + i) = w;
  } else if (blk < 4096) {
    const size_t i = ((size_t)(blk - 2048) * 256 + threadIdx.x) * 8;
    float4 xl = *(const float4*)(hs + i), xh = *(const float4*)(hs + i + 4);
    uint4 w;
    w.x = pk2(xl.x, xl.y); w.y = pk2(xl.z, xl.w);
    w.z = pk2(xh.x, xh.y); w.w = pk2(xh.z, xh.w);
    *(uint4*)(ohs + i) = w;
  } else {
    const int idx = (blk - 4096) * 256 + threadIdx.x;  // [0,4096)
    const int f = idx >> 6, o = idx & 63;
    const int k0 = o * 8;
    const size_t dst = ((size_t)((f >> 4) * 16 + (k0 >> 5)) << 9) +
                       (((f & 15) + 16 * ((k0 >> 3) & 3)) << 3);
    unsigned short w[8];
#pragma unroll
    for (int j = 0; j < 8; ++j) w[j] = f2bf(Wi[(size_t)(k0 + j) * Fn + f]);
    *(uint4*)(Wp + dst) = *(const uint4*)w;
  }
}

// ---------------------------------------------------------------------------
// MFMA GEMM, linear-A fragments + B-perm X, K-split (8 steps of K=32),
// depth-3 register prefetch, no LDS/barriers in K-loop.
// Block = (64 A-rows, b, slot). Output partial bf16 plane (slot*16+b),
// B-perm, via LDS transpose (contiguous stores).
// ---------------------------------------------------------------------------
struct Slot3 {
  const unsigned short* A;  // [16][512][512] linear bf16
  const unsigned short* X;  // B-perm [64f][512n] per b (xbs) or shared
  long long xbs;
  int kbase;                // 0 or 256
};
struct G3 {
  Slot3 s[12];
  unsigned short* O;
};

__launch_bounds__(256, 4)
__global__ void gemm_kernel(G3 g) {
  const int slot = blockIdx.z, b = blockIdx.y;
  const int R0 = blockIdx.x * 64;
  const int tid = threadIdx.x;
  const int w = tid >> 6, l = tid & 63;
  const int lr = l & 15, q = l >> 4;
  const Slot3 sl = g.s[slot];

  // A-frag (linear): lane reads row R0+w*16+lr, k = kbase + q*8 + t*32
  const unsigned short* Af = sl.A + ((size_t)b << 18) +
                             ((size_t)(R0 + w * 16 + lr) << 9) + sl.kbase + q * 8;
  // X-frag (B-perm): fragment t at offset t*512; kbase 256 -> +8 frags
  const unsigned short* Xf =
      sl.X + (size_t)b * sl.xbs + ((size_t)sl.kbase << 4) + l * 8;

  f32x4 acc[4] = {{0.f, 0.f, 0.f, 0.f},
                  {0.f, 0.f, 0.f, 0.f},
                  {0.f, 0.f, 0.f, 0.f},
                  {0.f, 0.f, 0.f, 0.f}};
  bf16x8 ab[3];
  bf16x8 xb[3][4];

#define LD(S_, T_)                                                        \
  {                                                                       \
    ab[S_] = *(const bf16x8*)(Af + (T_)*32);                              \
    _Pragma("unroll") for (int c = 0; c < 4; ++c) xb[S_][c] =             \
        *(const bf16x8*)(Xf + c * 8192 + (T_)*512);                      \
  }

  LD(0, 0) LD(1, 1) LD(2, 2)
#pragma unroll
  for (int t = 0; t < 8; ++t) {
    const int s3 = t % 3;
#pragma unroll
    for (int c = 0; c < 4; ++c)
      acc[c] =
          __builtin_amdgcn_mfma_f32_16x16x32_bf16(ab[s3], xb[s3][c], acc[c], 0, 0, 0);
    if (t + 3 < 8) LD(s3, t + 3)
  }
#undef LD

  // epilogue: LDS transpose -> B-perm contiguous stores
  __shared__ __align__(16) unsigned short T[64][72];
  const int rbase = w * 16 + q * 4;
#pragma unroll
  for (int c = 0; c < 4; ++c) {
#pragma unroll
    for (int i = 0; i < 4; ++i) T[c * 16 + lr][rbase + i] = f2bf(acc[c][i]);
  }
  __syncthreads();
  {
    const int f = tid >> 2, oc = tid & 3;
    unsigned short* Ob = g.O + (((size_t)slot * 16 + b) << 15);
#pragma unroll
    for (int p = 0; p < 2; ++p) {
      const int nl = oc * 8 + p * 32;
      const int nn = R0 + nl;
      const size_t dst = ((size_t)((f >> 4) * 16 + (nn >> 5)) << 9) +
                         (((f & 15) + 16 * ((nl >> 3) & 3)) << 3);
      *(uint4*)(Ob + dst) = *(const uint4*)&T[f][nl];
    }
  }
}

// ---------------------------------------------------------------------------
// h0bn: sum 2 split partials (B-perm planes 0,1), BN(n)+ReLU, write h0 B-perm.
// ---------------------------------------------------------------------------
__launch_bounds__(256)
__global__ void h0bn_kernel(const unsigned short* __restrict__ part,
                            const float* __restrict__ mean,
                            const float* __restrict__ var,
                            const float* __restrict__ gamma,
                            const float* __restrict__ beta,
                            unsigned short* __restrict__ h0p) {
  const int i = blockIdx.x * 256 + threadIdx.x;  // 65536 threads
  const int eg = i * 8;
  const int b = eg >> 15, e = eg & 32767;
  const int frag = e >> 9, p = (e >> 3) & 63;
  const int n0 = (frag & 15) * 32 + ((p >> 4) & 3) * 8;
  u16x8 u0 = *(const u16x8*)(part + ((size_t)b << 15) + e);
  u16x8 u1 = *(const u16x8*)(part + ((size_t)(16 + b) << 15) + e);
  float4 mn0 = *(const float4*)(mean + n0), mn1 = *(const float4*)(mean + n0 + 4);
  float4 vr0 = *(const float4*)(var + n0), vr1 = *(const float4*)(var + n0 + 4);
  float4 gm0 = *(const float4*)(gamma + n0), gm1 = *(const float4*)(gamma + n0 + 4);
  float4 bt0 = *(const float4*)(beta + n0), bt1 = *(const float4*)(beta + n0 + 4);
  float mn[8] = {mn0.x, mn0.y, mn0.z, mn0.w, mn1.x, mn1.y, mn1.z, mn1.w};
  float vr[8] = {vr0.x, vr0.y, vr0.z, vr0.w, vr1.x, vr1.y, vr1.z, vr1.w};
  float gm[8] = {gm0.x, gm0.y, gm0.z, gm0.w, gm1.x, gm1.y, gm1.z, gm1.w};
  float bt[8] = {bt0.x, bt0.y, bt0.z, bt0.w, bt1.x, bt1.y, bt1.z, bt1.w};
  u16x8 o;
#pragma unroll
  for (int j = 0; j < 8; ++j) {
    float v = bf2f((unsigned short)u0[j]) + bf2f((unsigned short)u1[j]);
    float sc = rsqrtf(vr[j] + 1e-5f) * gm[j];
    float r = fmaf(v - mn[j], sc, bt[j]);
    o[j] = f2bf(fmaxf(r, 0.f));
  }
  *(u16x8*)(h0p + ((size_t)b << 15) + e) = o;
}

// ---------------------------------------------------------------------------
// fuse: h_next = relu(BN(h@W3 + b + sum_z P_z@W_z)), P_z = sum of S partials.
// All bf16 tensor I/O in B-perm layout. Optionally emits summed P_z.
// ---------------------------------------------------------------------------
struct FArgs {
  const unsigned short* hT;
  const unsigned short* Pp;
  int S;
  const float *W3, *W0, *W1, *W2;
  const float *bias, *mean, *var, *gamma, *beta;
  unsigned short* outT;
  unsigned short* P0o;
  unsigned short* P1o;
  unsigned short* P2o;
};

__launch_bounds__(256)
__global__ void fuse_kernel(FArgs f) {
  const int b = blockIdx.y, nb = blockIdx.x;  // 16 blocks of 32 n
  const int t = threadIdx.x;
  __shared__ float sums[4][64][17];
  __shared__ __align__(16) unsigned short outH[64][40];
  __shared__ __align__(16) unsigned short outP[3][64][40];
  const int mat = t >> 6, k = t & 63;
  const int fo = t & 63, gq = t >> 6;
  const bool wantP = (f.P0o != nullptr);
  const float* Ws[4] = {f.W3, f.W0, f.W1, f.W2};

  for (int sub = 0; sub < 2; ++sub) {
    const int n0 = nb * 32 + sub * 16;
    const size_t fb = ((size_t)((k >> 4) * 16 + (n0 >> 5)) << 9) +
                      (((k & 15) + 16 * ((n0 >> 3) & 3)) << 3);
    float v[16];
    if (mat == 0) {
      const unsigned short* sp = f.hT + ((size_t)b << 15) + fb;
      u16x8 lo = *(const u16x8*)sp, hi = *(const u16x8*)(sp + 128);
#pragma unroll
      for (int e = 0; e < 8; ++e) {
        v[e] = bf2f((unsigned short)lo[e]);
        v[8 + e] = bf2f((unsigned short)hi[e]);
      }
    } else {
#pragma unroll
      for (int e = 0; e < 16; ++e) v[e] = 0.f;
      const int z = mat - 1;
      for (int sp2 = 0; sp2 < f.S; ++sp2) {
        const unsigned short* p =
            f.Pp + ((((size_t)z * f.S + sp2) * 16 + b) << 15) + fb;
        u16x8 lo = *(const u16x8*)p, hi = *(const u16x8*)(p + 128);
#pragma unroll
        for (int e = 0; e < 8; ++e) {
          v[e] += bf2f((unsigned short)lo[e]);
          v[8 + e] += bf2f((unsigned short)hi[e]);
        }
      }
    }
#pragma unroll
    for (int e = 0; e < 16; ++e) sums[mat][k][e] = v[e];
    if (wantP && mat >= 1) {
      u16x8 pw0, pw1;
#pragma unroll
      for (int e = 0; e < 8; ++e) {
        pw0[e] = f2bf(v[e]);
        pw1[e] = f2bf(v[8 + e]);
      }
      *(u16x8*)&outP[mat - 1][k][sub * 16] = pw0;
      *(u16x8*)&outP[mat - 1][k][sub * 16 + 8] = pw1;
    }
    __syncthreads();
    float acc[4] = {f.bias[fo], f.bias[fo], f.bias[fo], f.bias[fo]};
#pragma unroll
    for (int m2 = 0; m2 < 4; ++m2) {
      const float* __restrict__ W = Ws[m2];
#pragma unroll 8
      for (int k2 = 0; k2 < 64; ++k2) {
        float wv = W[k2 * 64 + fo];
#pragma unroll
        for (int i = 0; i < 4; ++i)
          acc[i] = fmaf(sums[m2][k2][gq * 4 + i], wv, acc[i]);
      }
    }
    ushort4 ov;
#pragma unroll
    for (int i = 0; i < 4; ++i) {
      int n = n0 + gq * 4 + i;
      float sc = rsqrtf(f.var[n] + 1e-5f) * f.gamma[n];
      float r = fmaf(acc[i] - f.mean[n], sc, f.beta[n]);
      ((unsigned short*)&ov)[i] = f2bf(fmaxf(r, 0.f));
    }
    *(ushort4*)&outH[fo][sub * 16 + gq * 4] = ov;
    __syncthreads();
  }

  const int fr = t >> 2, oc = t & 3;
  const int n0w = nb * 32 + oc * 8;
  const size_t dst = ((size_t)b << 15) +
                     ((size_t)((fr >> 4) * 16 + (n0w >> 5)) << 9) +
                     (((fr & 15) + 16 * ((n0w >> 3) & 3)) << 3);
  *(u16x8*)(f.outT + dst) = *(const u16x8*)&outH[fr][oc * 8];
  if (wantP) {
    *(u16x8*)(f.P0o + dst) = *(const u16x8*)&outP[0][fr][oc * 8];
    *(u16x8*)(f.P1o + dst) = *(const u16x8*)&outP[1][fr][oc * 8];
    *(u16x8*)(f.P2o + dst) = *(const u16x8*)&outP[2][fr][oc * 8];
  }
}

// ---------------------------------------------------------------------------
// head: sum over n (B-perm h3) -> BN+ReLU -> FC(512) -> softmax. block per b.
// ---------------------------------------------------------------------------
__launch_bounds__(256)
__global__ void head_kernel(const unsigned short* __restrict__ h3p,
                            const float* __restrict__ gmean,
                            const float* __restrict__ gvar,
                            const float* __restrict__ ggamma,
                            const float* __restrict__ gbeta,
                            const float* __restrict__ fc_w,
                            const float* __restrict__ fc_b,
                            float* __restrict__ out) {
  const int b = blockIdx.x;
  const int t = threadIdx.x;
  __shared__ float part[256];
  __shared__ float gh[64];
  __shared__ float red[256];

  const int f = t >> 2, q = t & 3;
  const unsigned short* hp = h3p + ((size_t)b << 15);
  float s = 0.f;
#pragma unroll
  for (int m = 0; m < 16; ++m) {
    const int n = q * 128 + m * 8;
    const size_t off = ((size_t)((f >> 4) * 16 + (n >> 5)) << 9) +
                       (((f & 15) + 16 * ((n >> 3) & 3)) << 3);
    u16x8 v = *(const u16x8*)(hp + off);
#pragma unroll
    for (int e = 0; e < 8; ++e) s += bf2f((unsigned short)v[e]);
  }
  part[t] = s;
  __syncthreads();
  if (t < 64) {
    float sum = part[t * 4] + part[t * 4 + 1] + part[t * 4 + 2] + part[t * 4 + 3];
    float sc = rsqrtf(gvar[t] + 1e-5f) * ggamma[t];
    float v = fmaf(sum - gmean[t], sc, gbeta[t]);
    gh[t] = v > 0.f ? v : 0.f;
  }
  __syncthreads();

  float lg[2];
#pragma unroll
  for (int rep = 0; rep < 2; ++rep) {
    const int a = t + rep * 256;
    const float* __restrict__ wv = fc_w + (size_t)a * Fn;
    float acc = fc_b[a];
#pragma unroll 8
    for (int kk = 0; kk < 64; ++kk) acc = fmaf(gh[kk], wv[kk], acc);
    lg[rep] = acc;
  }
  red[t] = fmaxf(lg[0], lg[1]);
  __syncthreads();
  for (int off = 128; off > 0; off >>= 1) {
    if (t < off) red[t] = fmaxf(red[t], red[t + off]);
    __syncthreads();
  }
  const float mx = red[0];
  __syncthreads();
  const float e0 = __expf(lg[0] - mx), e1 = __expf(lg[1] - mx);
  red[t] = e0 + e1;
  __syncthreads();
  for (int off = 128; off > 0; off >>= 1) {
    if (t < off) red[t] += red[t + off];
    __syncthreads();
  }
  const float inv = 1.f / red[0];
  out[(size_t)b * Aout + t] = e0 * inv;
  out[(size_t)b * Aout + t + 256] = e1 * inv;
}

// ---------------------------------------------------------------------------
extern "C" void kernel_launch(void* const* d_in, const int* in_sizes, int n_in,
                              void* d_out, int out_size, void* d_ws,
                              size_t ws_size, hipStream_t stream) {
  (void)in_sizes; (void)n_in; (void)out_size; (void)ws_size;
  const float* hs_init = (const float*)d_in[0];
  const float* adjs0 = (const float*)d_in[1];
  const float* adjs1 = (const float*)d_in[2];
  const float* adjs2 = (const float*)d_in[3];
  const float* W_init = (const float*)d_in[4];
  const float* W0 = (const float*)d_in[5];
  const float* W1 = (const float*)d_in[6];
  const float* W2 = (const float*)d_in[7];
  const float* W3 = (const float*)d_in[8];
  const float* bvec = (const float*)d_in[9];
  const float* fc1_w = (const float*)d_in[10];
  const float* fc1_b = (const float*)d_in[11];
  const float* bn_init_mean = (const float*)d_in[12];
  const float* bn_init_var = (const float*)d_in[13];
  const float* bn_init_gamma = (const float*)d_in[14];
  const float* bn_init_beta = (const float*)d_in[15];
  const float* bn_layer_mean = (const float*)d_in[16];
  const float* bn_layer_var = (const float*)d_in[17];
  const float* bn_layer_gamma = (const float*)d_in[18];
  const float* bn_layer_beta = (const float*)d_in[19];
  const float* bn_graph_mean = (const float*)d_in[20];
  const float* bn_graph_var = (const float*)d_in[21];
  const float* bn_graph_gamma = (const float*)d_in[22];
  const float* bn_graph_beta = (const float*)d_in[23];

  const size_t ADJ = (size_t)Bn * Nn * Nn;  // 4,194,304
  const size_t NF = (size_t)Bn * Fn * Nn;   // 524,288

  unsigned short* wsu = (unsigned short*)d_ws;
  unsigned short* a0b = wsu;
  unsigned short* a1b = a0b + ADJ;
  unsigned short* a2b = a1b + ADJ;
  unsigned short* asumb = a2b + ADJ;
  unsigned short* hsb = asumb + ADJ;
  unsigned short* Wp = hsb + ADJ;  // 32768
  unsigned short* h0p = Wp + 32768;
  unsigned short* h1p = h0p + NF;
  unsigned short* h2p = h1p + NF;
  unsigned short* h3p = h2p + NF;
  unsigned short* P0p = h3p + NF;
  unsigned short* P1p = P0p + NF;
  unsigned short* P2p = P1p + NF;
  unsigned short* part = P2p + NF;  // up to 12 planes

  // 1) prep (streaming converts)
  prep_kernel<<<dim3(4096 + 16), dim3(256), 0, stream>>>(
      adjs0, adjs1, adjs2, hs_init, a0b, a1b, a2b, asumb, hsb, W_init, Wp);

  // 2) h0 partials: hs @ Wi, ksplit 2
  {
    G3 a = {};
    a.s[0] = {hsb, Wp, 0, 0};
    a.s[1] = {hsb, Wp, 0, 256};
    a.O = part;
    gemm_kernel<<<dim3(8, Bn, 2), dim3(256), 0, stream>>>(a);
  }
  // 3) h0 = relu(BN_init(sum))
  h0bn_kernel<<<dim3(256), dim3(256), 0, stream>>>(
      part, bn_init_mean, bn_init_var, bn_init_gamma, bn_init_beta, h0p);

  const unsigned short* ab2[3] = {a0b, a1b, a2b};

  // 4) L0: slots z*2+c = a_z @ h0 (ksplit c)
  {
    G3 a = {};
    for (int z = 0; z < 3; ++z)
      for (int c = 0; c < 2; ++c) a.s[z * 2 + c] = {ab2[z], h0p, 32768, c * 256};
    a.O = part;
    gemm_kernel<<<dim3(8, Bn, 6), dim3(256), 0, stream>>>(a);
  }
  // 5) fuse L0 (S=2) -> h1, P_z[0]
  {
    FArgs fa = {};
    fa.hT = h0p; fa.Pp = part; fa.S = 2;
    fa.W3 = W3; fa.W0 = W0; fa.W1 = W1; fa.W2 = W2;
    fa.bias = bvec; fa.mean = bn_layer_mean; fa.var = bn_layer_var;
    fa.gamma = bn_layer_gamma; fa.beta = bn_layer_beta;
    fa.outT = h1p; fa.P0o = P0p; fa.P1o = P1p; fa.P2o = P2p;
    fuse_kernel<<<dim3(16, Bn), dim3(256), 0, stream>>>(fa);
  }

  const unsigned short* Ps[3] = {P0p, P1p, P2p};

  // 6) L1: slots z*4+{0,1} = a_z @ h1; z*4+{2,3} = asum @ P_z[0]
  {
    G3 a = {};
    for (int z = 0; z < 3; ++z)
      for (int c = 0; c < 2; ++c) {
        a.s[z * 4 + c] = {ab2[z], h1p, 32768, c * 256};
        a.s[z * 4 + 2 + c] = {asumb, Ps[z], 32768, c * 256};
      }
    a.O = part;
    gemm_kernel<<<dim3(8, Bn, 12), dim3(256), 0, stream>>>(a);
  }
  // 7) fuse L1 (S=4) -> h2, P_z[1]
  {
    FArgs fa = {};
    fa.hT = h1p; fa.Pp = part; fa.S = 4;
    fa.W3 = W3 + 4096; fa.W0 = W0 + 4096; fa.W1 = W1 + 4096; fa.W2 = W2 + 4096;
    fa.bias = bvec + 64; fa.mean = bn_layer_mean + 512;
    fa.var = bn_layer_var + 512; fa.gamma = bn_layer_gamma + 512;
    fa.beta = bn_layer_beta + 512;
    fa.outT = h2p; fa.P0o = P0p; fa.P1o = P1p; fa.P2o = P2p;
    fuse_kernel<<<dim3(16, Bn), dim3(256), 0, stream>>>(fa);
  }

  // 8) L2
  {
    G3 a = {};
    for (int z = 0; z < 3; ++z)
      for (int c = 0; c < 2; ++c) {
        a.s[z * 4 + c] = {ab2[z], h2p, 32768, c * 256};
        a.s[z * 4 + 2 + c] = {asumb, Ps[z], 32768, c * 256};
      }
    a.O = part;
    gemm_kernel<<<dim3(8, Bn, 12), dim3(256), 0, stream>>>(a);
  }
  // 9) fuse L2 (S=4) -> h3
  {
    FArgs fa = {};
    fa.hT = h2p; fa.Pp = part; fa.S = 4;
    fa.W3 = W3 + 8192; fa.W0 = W0 + 8192; fa.W1 = W1 + 8192; fa.W2 = W2 + 8192;
    fa.bias = bvec + 128; fa.mean = bn_layer_mean + 1024;
    fa.var = bn_layer_var + 1024; fa.gamma = bn_layer_gamma + 1024;
    fa.beta = bn_layer_beta + 1024;
    fa.outT = h3p; fa.P0o = nullptr; fa.P1o = nullptr; fa.P2o = nullptr;
    fuse_kernel<<<dim3(16, Bn), dim3(256), 0, stream>>>(fa);
  }

  // 10) head
  head_kernel<<<dim3(Bn), dim3(256), 0, stream>>>(
      h3p, bn_graph_mean, bn_graph_var, bn_graph_gamma, bn_graph_beta, fc1_w,
      fc1_b, (float*)d_out);
}

// Round 9
// 92.502 us; speedup vs baseline: 2.0636x; 1.5657x over previous
//
#include <hip/hip_runtime.h>

typedef __attribute__((ext_vector_type(8))) short bf16x8;
typedef __attribute__((ext_vector_type(4))) float f32x4;
typedef __attribute__((ext_vector_type(8))) unsigned short u16x8;

constexpr int Bn = 16;
constexpr int Nn = 512;
constexpr int Fn = 64;
constexpr int Aout = 512;

static __device__ __forceinline__ unsigned short f2bf(float f) {
  union { float f; unsigned int u; } v; v.f = f;
  unsigned int r = v.u + 0x7fffu + ((v.u >> 16) & 1u);
  return (unsigned short)(r >> 16);
}
static __device__ __forceinline__ float bf2f(unsigned short u) {
  union { unsigned int u; float f; } v; v.u = ((unsigned int)u) << 16;
  return v.f;
}
static __device__ __forceinline__ unsigned int pk2(float a, float b) {
  union { float f; unsigned int u; } ua, ub; ua.f = a; ub.f = b;
  return ((ua.u + 0x8000u) >> 16) | ((ub.u + 0x8000u) & 0xFFFF0000u);
}

// B-perm (X/B-operand fragment layout), cols c, contraction k, K total:
//   frag = (c>>4)*(K/32) + (k>>5); off = frag*512 + ((c&15) + 16*((k>>3)&3))*8 + (k&7)

// ---------------------------------------------------------------------------
// prep:
// [0,2048): adjs0/1/2 -> linear bf16 + bf16 sum (8 elems/thread, streaming)
// [2048,4096): hs_init -> linear bf16
// [4096,4112): W_init -> B-perm (K=512)
// [4112,4136): W3/W0/W1/W2 per layer -> B-perm (K=64), order [l][W3,W0,W1,W2]
// ---------------------------------------------------------------------------
__launch_bounds__(256)
__global__ void prep_kernel(const float* __restrict__ a0,
                            const float* __restrict__ a1,
                            const float* __restrict__ a2,
                            const float* __restrict__ hs,
                            unsigned short* __restrict__ o0,
                            unsigned short* __restrict__ o1,
                            unsigned short* __restrict__ o2,
                            unsigned short* __restrict__ osum,
                            unsigned short* __restrict__ ohs,
                            const float* __restrict__ Wi,
                            unsigned short* __restrict__ Wp,
                            const float* __restrict__ W0,
                            const float* __restrict__ W1,
                            const float* __restrict__ W2,
                            const float* __restrict__ W3,
                            unsigned short* __restrict__ Wall) {
  const int blk = blockIdx.x;
  if (blk < 2048) {
    const size_t i = ((size_t)blk * 256 + threadIdx.x) * 8;
    float4 xl = *(const float4*)(a0 + i), xh = *(const float4*)(a0 + i + 4);
    float4 yl = *(const float4*)(a1 + i), yh = *(const float4*)(a1 + i + 4);
    float4 zl = *(const float4*)(a2 + i), zh = *(const float4*)(a2 + i + 4);
    uint4 w;
    w.x = pk2(xl.x, xl.y); w.y = pk2(xl.z, xl.w);
    w.z = pk2(xh.x, xh.y); w.w = pk2(xh.z, xh.w);
    *(uint4*)(o0 + i) = w;
    w.x = pk2(yl.x, yl.y); w.y = pk2(yl.z, yl.w);
    w.z = pk2(yh.x, yh.y); w.w = pk2(yh.z, yh.w);
    *(uint4*)(o1 + i) = w;
    w.x = pk2(zl.x, zl.y); w.y = pk2(zl.z, zl.w);
    w.z = pk2(zh.x, zh.y); w.w = pk2(zh.z, zh.w);
    *(uint4*)(o2 + i) = w;
    w.x = pk2(xl.x + yl.x + zl.x, xl.y + yl.y + zl.y);
    w.y = pk2(xl.z + yl.z + zl.z, xl.w + yl.w + zl.w);
    w.z = pk2(xh.x + yh.x + zh.x, xh.y + yh.y + zh.y);
    w.w = pk2(xh.z + yh.z + zh.z, xh.w + yh.w + zh.w);
    *(uint4*)(osum + i) = w;
  } else if (blk < 4096) {
    const size_t i = ((size_t)(blk - 2048) * 256 + threadIdx.x) * 8;
    float4 xl = *(const float4*)(hs + i), xh = *(const float4*)(hs + i + 4);
    uint4 w;
    w.x = pk2(xl.x, xl.y); w.y = pk2(xl.z, xl.w);
    w.z = pk2(xh.x, xh.y); w.w = pk2(xh.z, xh.w);
    *(uint4*)(ohs + i) = w;
  } else if (blk < 4112) {
    const int idx = (blk - 4096) * 256 + threadIdx.x;  // [0,4096)
    const int f = idx >> 6, o = idx & 63;
    const int k0 = o * 8;
    const size_t dst = ((size_t)((f >> 4) * 16 + (k0 >> 5)) << 9) +
                       (((f & 15) + 16 * ((k0 >> 3) & 3)) << 3);
    unsigned short w[8];
#pragma unroll
    for (int j = 0; j < 8; ++j) w[j] = f2bf(Wi[(size_t)(k0 + j) * Fn + f]);
    *(uint4*)(Wp + dst) = *(const uint4*)w;
  } else {
    // layer weights: 12 matrices of 64x64, 2 blocks each
    const int r = blk - 4112;
    const int mat = r >> 1;               // 0..11 = l*4 + m (m: W3,W0,W1,W2)
    const int l = mat >> 2, m = mat & 3;
    const int idx = (r & 1) * 256 + threadIdx.x;  // [0,512)
    const int co = idx >> 3, oct = idx & 7;
    const int k0 = oct * 8;
    const float* src = (m == 0 ? W3 : m == 1 ? W0 : m == 2 ? W1 : W2) + l * 4096;
    const size_t dst = (size_t)mat * 4096 +
                       ((size_t)((co >> 4) * 2 + (k0 >> 5)) << 9) +
                       (((co & 15) + 16 * ((k0 >> 3) & 3)) << 3);
    unsigned short w[8];
#pragma unroll
    for (int j = 0; j < 8; ++j) w[j] = f2bf(src[(k0 + j) * 64 + co]);
    *(uint4*)(Wall + dst) = *(const uint4*)w;
  }
}

// ---------------------------------------------------------------------------
// h0 kernel: h0 = relu(BN_init(hs @ Wi)), K=512 fragment-direct MFMA.
// Block = 64 rows x 64 f, grid (8, 16). Outputs B-perm AND linear layouts.
// ---------------------------------------------------------------------------
__launch_bounds__(256, 1)
__global__ void h0_kernel(const unsigned short* __restrict__ hsb,
                          const unsigned short* __restrict__ Wp,
                          const float* __restrict__ mean,
                          const float* __restrict__ var,
                          const float* __restrict__ gamma,
                          const float* __restrict__ beta,
                          unsigned short* __restrict__ operm,
                          unsigned short* __restrict__ olin) {
  const int b = blockIdx.y;
  const int R0 = blockIdx.x * 64;
  const int tid = threadIdx.x;
  const int w = tid >> 6, l = tid & 63;
  const int lr = l & 15, q = l >> 4;

  const unsigned short* Af =
      hsb + ((size_t)b << 18) + ((size_t)(R0 + w * 16 + lr) << 9) + q * 8;
  const unsigned short* Xf = Wp + l * 8;

  f32x4 acc[4] = {{0.f, 0.f, 0.f, 0.f}, {0.f, 0.f, 0.f, 0.f},
                  {0.f, 0.f, 0.f, 0.f}, {0.f, 0.f, 0.f, 0.f}};
  bf16x8 ab[3];
  bf16x8 xb[3][4];
#define LD0(S_, T_)                                                    \
  {                                                                    \
    ab[S_] = *(const bf16x8*)(Af + (T_)*32);                           \
    _Pragma("unroll") for (int c = 0; c < 4; ++c) xb[S_][c] =          \
        *(const bf16x8*)(Xf + c * 8192 + (T_)*512);                    \
  }
  LD0(0, 0) LD0(1, 1) LD0(2, 2)
#pragma unroll
  for (int t = 0; t < 16; ++t) {
    const int s3 = t % 3;
#pragma unroll
    for (int c = 0; c < 4; ++c)
      acc[c] = __builtin_amdgcn_mfma_f32_16x16x32_bf16(ab[s3], xb[s3][c], acc[c], 0, 0, 0);
    if (t + 3 < 16) LD0(s3, t + 3)
  }
#undef LD0

  __shared__ __align__(16) unsigned short Tfn[64][72];  // [f][n]
  __shared__ __align__(16) unsigned short Tnf[64][72];  // [n][f]
  const int rbase = w * 16 + q * 4;
  float sc[4], mu[4], bt[4];
#pragma unroll
  for (int i = 0; i < 4; ++i) {
    int n = R0 + rbase + i;
    sc[i] = rsqrtf(var[n] + 1e-5f) * gamma[n];
    mu[i] = mean[n];
    bt[i] = beta[n];
  }
#pragma unroll
  for (int c = 0; c < 4; ++c) {
    ushort4 wv;
#pragma unroll
    for (int i = 0; i < 4; ++i) {
      float v = fmaxf(fmaf(acc[c][i] - mu[i], sc[i], bt[i]), 0.f);
      unsigned short uv = f2bf(v);
      ((unsigned short*)&wv)[i] = uv;
      Tnf[rbase + i][c * 16 + lr] = uv;
    }
    *(ushort4*)&Tfn[c * 16 + lr][rbase] = wv;
  }
  __syncthreads();
  {
    // B-perm store
    const int f = tid >> 2, oc = tid & 3;
    unsigned short* Ob = operm + ((size_t)b << 15);
#pragma unroll
    for (int p = 0; p < 2; ++p) {
      const int nl = oc * 8 + p * 32;
      const int nn = R0 + nl;
      const size_t dst = ((size_t)((f >> 4) * 16 + (nn >> 5)) << 9) +
                         (((f & 15) + 16 * ((nl >> 3) & 3)) << 3);
      *(uint4*)(Ob + dst) = *(const uint4*)&Tfn[f][nl];
    }
    // linear store
    const int n = tid >> 2;
    unsigned short* Ol = olin + ((size_t)b << 15) + (size_t)(R0 + n) * 64 + oc * 16;
    *(uint4*)Ol = *(const uint4*)&Tnf[n][oc * 16];
    *(uint4*)(Ol + 8) = *(const uint4*)&Tnf[n][oc * 16 + 8];
  }
}

// ---------------------------------------------------------------------------
// layer kernel: per block (32 n-rows, b):
//  phase A: P_z = a_z@h (+ asum@P_z_old if NSEG==2), z=0..2, MFMA K=512/1024
//  store P_z (B-perm) ; phase B: h_tmp = h@W3 + sum_z P_z@W_z (MFMA K=64)
//  epilogue: +bias, BN(n), ReLU -> h_next (B-perm + linear)
// ---------------------------------------------------------------------------
struct LArgs {
  const unsigned short* Az[3];
  const unsigned short* Asum;
  const unsigned short* Xh;     // h B-perm
  const unsigned short* XP[3];  // P_old B-perm (NSEG==2)
  const unsigned short* hlin;   // h linear [n][f]
  const unsigned short* Wl;     // 4 mats B-perm K=64: [W3,W0,W1,W2]
  const float *bias, *mean, *var, *gamma, *beta;
  unsigned short* hperm_o;
  unsigned short* hlin_o;       // null -> skip
  unsigned short* Po[3];        // null -> skip
};

template <int NSEG>
__launch_bounds__(256, 1)
__global__ void layer_kernel(LArgs La) {
  const int b = blockIdx.y;
  const int R0 = blockIdx.x * 32;
  const int tid = threadIdx.x;
  const int w = tid >> 6, l = tid & 63;
  const int lr = l & 15, q = l >> 4;
  const int nsub = (w & 1) * 16;
  const int cstart = (w >> 1) * 2;

  __shared__ __align__(16) unsigned short Tnf[3][32][72];  // [z][n][f]
  __shared__ __align__(16) unsigned short Tfn[3][64][40];  // [z][f][n]
  __shared__ __align__(16) unsigned short Hfn[64][40];     // h_next [f][n]
  __shared__ __align__(16) unsigned short Hnf[32][72];     // h_next [n][f]

  f32x4 acc[3][2];
#pragma unroll
  for (int z = 0; z < 3; ++z)
#pragma unroll
    for (int c = 0; c < 2; ++c) acc[z][c] = {0.f, 0.f, 0.f, 0.f};

#pragma unroll
  for (int z = 0; z < 3; ++z) {
#pragma unroll
    for (int seg = 0; seg < NSEG; ++seg) {
      const unsigned short* Af =
          (seg == 0 ? La.Az[z] : La.Asum) + ((size_t)b << 18) +
          ((size_t)(R0 + nsub + lr) << 9) + q * 8;
      const unsigned short* Xf = (seg == 0 ? La.Xh : La.XP[z]) +
                                 ((size_t)b << 15) + cstart * 8192 + l * 8;
      bf16x8 a2[2], x2[2][2];
      a2[0] = *(const bf16x8*)Af;
      x2[0][0] = *(const bf16x8*)Xf;
      x2[0][1] = *(const bf16x8*)(Xf + 8192);
      a2[1] = *(const bf16x8*)(Af + 32);
      x2[1][0] = *(const bf16x8*)(Xf + 512);
      x2[1][1] = *(const bf16x8*)(Xf + 8192 + 512);
#pragma unroll
      for (int t = 0; t < 16; ++t) {
        const int cur = t & 1;
        acc[z][0] = __builtin_amdgcn_mfma_f32_16x16x32_bf16(a2[cur], x2[cur][0],
                                                            acc[z][0], 0, 0, 0);
        acc[z][1] = __builtin_amdgcn_mfma_f32_16x16x32_bf16(a2[cur], x2[cur][1],
                                                            acc[z][1], 0, 0, 0);
        if (t + 2 < 16) {
          a2[cur] = *(const bf16x8*)(Af + (t + 2) * 32);
          x2[cur][0] = *(const bf16x8*)(Xf + (t + 2) * 512);
          x2[cur][1] = *(const bf16x8*)(Xf + 8192 + (t + 2) * 512);
        }
      }
    }
  }

  // stage P_z tiles to LDS in both layouts
#pragma unroll
  for (int z = 0; z < 3; ++z) {
#pragma unroll
    for (int c = 0; c < 2; ++c) {
      const int f = (cstart + c) * 16 + lr;
      ushort4 wv;
#pragma unroll
      for (int i = 0; i < 4; ++i) {
        unsigned short uv = f2bf(acc[z][c][i]);
        ((unsigned short*)&wv)[i] = uv;
        Tnf[z][nsub + q * 4 + i][f] = uv;
      }
      *(ushort4*)&Tfn[z][f][nsub + q * 4] = wv;
    }
  }
  __syncthreads();

  // P_z global stores (B-perm)
  if (La.Po[0] != nullptr) {
    const int f = tid >> 2, oc = tid & 3;
    const int nl = oc * 8;
    const size_t dst = ((size_t)b << 15) +
                       ((size_t)((f >> 4) * 16 + (R0 >> 5)) << 9) +
                       (((f & 15) + 16 * ((nl >> 3) & 3)) << 3);
#pragma unroll
    for (int z = 0; z < 3; ++z)
      *(uint4*)(La.Po[z] + dst) = *(const uint4*)&Tfn[z][f][nl];
  }

  // phase B: h_tmp = h@W3 + sum_z P_z@W_z  (contraction over f=64)
  f32x4 acch[2] = {{0.f, 0.f, 0.f, 0.f}, {0.f, 0.f, 0.f, 0.f}};
#pragma unroll
  for (int m = 0; m < 4; ++m) {
#pragma unroll
    for (int ks = 0; ks < 2; ++ks) {
      bf16x8 af;
      if (m == 0)
        af = *(const bf16x8*)(La.hlin + ((size_t)b << 15) +
                              (size_t)(R0 + nsub + lr) * 64 + q * 8 + ks * 32);
      else
        af = *(const bf16x8*)&Tnf[m - 1][nsub + lr][q * 8 + ks * 32];
#pragma unroll
      for (int c = 0; c < 2; ++c) {
        const bf16x8 bf_ = *(const bf16x8*)(
            La.Wl + m * 4096 + ((size_t)((cstart + c) * 2 + ks) << 9) + l * 8);
        acch[c] =
            __builtin_amdgcn_mfma_f32_16x16x32_bf16(af, bf_, acch[c], 0, 0, 0);
      }
    }
  }
  __syncthreads();

  // epilogue: bias + BN + ReLU -> Hfn/Hnf
  {
    float sc[4], mu[4], bt[4];
#pragma unroll
    for (int i = 0; i < 4; ++i) {
      int n = R0 + nsub + q * 4 + i;
      sc[i] = rsqrtf(La.var[n] + 1e-5f) * La.gamma[n];
      mu[i] = La.mean[n];
      bt[i] = La.beta[n];
    }
#pragma unroll
    for (int c = 0; c < 2; ++c) {
      const int f = (cstart + c) * 16 + lr;
      const float bia = La.bias[f];
      ushort4 wv;
#pragma unroll
      for (int i = 0; i < 4; ++i) {
        float v = acch[c][i] + bia;
        v = fmaxf(fmaf(v - mu[i], sc[i], bt[i]), 0.f);
        unsigned short uv = f2bf(v);
        ((unsigned short*)&wv)[i] = uv;
        Hnf[nsub + q * 4 + i][f] = uv;
      }
      *(ushort4*)&Hfn[f][nsub + q * 4] = wv;
    }
  }
  __syncthreads();

  // h_next global stores
  {
    const int f = tid >> 2, oc = tid & 3;
    const int nl = oc * 8;
    const size_t dst = ((size_t)b << 15) +
                       ((size_t)((f >> 4) * 16 + (R0 >> 5)) << 9) +
                       (((f & 15) + 16 * ((nl >> 3) & 3)) << 3);
    *(uint4*)(La.hperm_o + dst) = *(const uint4*)&Hfn[f][nl];
    if (La.hlin_o != nullptr) {
      const int n = tid >> 3, oc8 = tid & 7;
      unsigned short* Ol =
          La.hlin_o + ((size_t)b << 15) + (size_t)(R0 + n) * 64 + oc8 * 8;
      *(uint4*)Ol = *(const uint4*)&Hnf[n][oc8 * 8];
    }
  }
}

// ---------------------------------------------------------------------------
// head: sum over n (B-perm h3) -> BN+ReLU -> FC(512) -> softmax. block per b.
// ---------------------------------------------------------------------------
__launch_bounds__(256)
__global__ void head_kernel(const unsigned short* __restrict__ h3p,
                            const float* __restrict__ gmean,
                            const float* __restrict__ gvar,
                            const float* __restrict__ ggamma,
                            const float* __restrict__ gbeta,
                            const float* __restrict__ fc_w,
                            const float* __restrict__ fc_b,
                            float* __restrict__ out) {
  const int b = blockIdx.x;
  const int t = threadIdx.x;
  __shared__ float part[256];
  __shared__ float gh[64];
  __shared__ float red[256];

  const int f = t >> 2, q = t & 3;
  const unsigned short* hp = h3p + ((size_t)b << 15);
  float s = 0.f;
#pragma unroll
  for (int m = 0; m < 16; ++m) {
    const int n = q * 128 + m * 8;
    const size_t off = ((size_t)((f >> 4) * 16 + (n >> 5)) << 9) +
                       (((f & 15) + 16 * ((n >> 3) & 3)) << 3);
    u16x8 v = *(const u16x8*)(hp + off);
#pragma unroll
    for (int e = 0; e < 8; ++e) s += bf2f((unsigned short)v[e]);
  }
  part[t] = s;
  __syncthreads();
  if (t < 64) {
    float sum = part[t * 4] + part[t * 4 + 1] + part[t * 4 + 2] + part[t * 4 + 3];
    float sc = rsqrtf(gvar[t] + 1e-5f) * ggamma[t];
    float v = fmaf(sum - gmean[t], sc, gbeta[t]);
    gh[t] = v > 0.f ? v : 0.f;
  }
  __syncthreads();

  float lg[2];
#pragma unroll
  for (int rep = 0; rep < 2; ++rep) {
    const int a = t + rep * 256;
    const float* __restrict__ wv = fc_w + (size_t)a * Fn;
    float acc = fc_b[a];
#pragma unroll 8
    for (int kk = 0; kk < 64; ++kk) acc = fmaf(gh[kk], wv[kk], acc);
    lg[rep] = acc;
  }
  red[t] = fmaxf(lg[0], lg[1]);
  __syncthreads();
  for (int off = 128; off > 0; off >>= 1) {
    if (t < off) red[t] = fmaxf(red[t], red[t + off]);
    __syncthreads();
  }
  const float mx = red[0];
  __syncthreads();
  const float e0 = __expf(lg[0] - mx), e1 = __expf(lg[1] - mx);
  red[t] = e0 + e1;
  __syncthreads();
  for (int off = 128; off > 0; off >>= 1) {
    if (t < off) red[t] += red[t + off];
    __syncthreads();
  }
  const float inv = 1.f / red[0];
  out[(size_t)b * Aout + t] = e0 * inv;
  out[(size_t)b * Aout + t + 256] = e1 * inv;
}

// ---------------------------------------------------------------------------
extern "C" void kernel_launch(void* const* d_in, const int* in_sizes, int n_in,
                              void* d_out, int out_size, void* d_ws,
                              size_t ws_size, hipStream_t stream) {
  (void)in_sizes; (void)n_in; (void)out_size; (void)ws_size;
  const float* hs_init = (const float*)d_in[0];
  const float* adjs0 = (const float*)d_in[1];
  const float* adjs1 = (const float*)d_in[2];
  const float* adjs2 = (const float*)d_in[3];
  const float* W_init = (const float*)d_in[4];
  const float* W0 = (const float*)d_in[5];
  const float* W1 = (const float*)d_in[6];
  const float* W2 = (const float*)d_in[7];
  const float* W3 = (const float*)d_in[8];
  const float* bvec = (const float*)d_in[9];
  const float* fc1_w = (const float*)d_in[10];
  const float* fc1_b = (const float*)d_in[11];
  const float* bn_init_mean = (const float*)d_in[12];
  const float* bn_init_var = (const float*)d_in[13];
  const float* bn_init_gamma = (const float*)d_in[14];
  const float* bn_init_beta = (const float*)d_in[15];
  const float* bn_layer_mean = (const float*)d_in[16];
  const float* bn_layer_var = (const float*)d_in[17];
  const float* bn_layer_gamma = (const float*)d_in[18];
  const float* bn_layer_beta = (const float*)d_in[19];
  const float* bn_graph_mean = (const float*)d_in[20];
  const float* bn_graph_var = (const float*)d_in[21];
  const float* bn_graph_gamma = (const float*)d_in[22];
  const float* bn_graph_beta = (const float*)d_in[23];

  const size_t ADJ = (size_t)Bn * Nn * Nn;  // 4,194,304
  const size_t NF = (size_t)Bn * Fn * Nn;   // 524,288

  unsigned short* wsu = (unsigned short*)d_ws;
  unsigned short* a0b = wsu;
  unsigned short* a1b = a0b + ADJ;
  unsigned short* a2b = a1b + ADJ;
  unsigned short* asumb = a2b + ADJ;
  unsigned short* hsb = asumb + ADJ;
  unsigned short* Wp = hsb + ADJ;       // 32768
  unsigned short* Wall = Wp + 32768;    // 49152
  unsigned short* hApe = Wall + 49152;
  unsigned short* hBpe = hApe + NF;
  unsigned short* hAli = hBpe + NF;
  unsigned short* hBli = hAli + NF;
  unsigned short* PA0 = hBli + NF;
  unsigned short* PA1 = PA0 + NF;
  unsigned short* PA2 = PA1 + NF;
  unsigned short* PB0 = PA2 + NF;
  unsigned short* PB1 = PB0 + NF;
  unsigned short* PB2 = PB1 + NF;

  // 1) prep
  prep_kernel<<<dim3(4136), dim3(256), 0, stream>>>(
      adjs0, adjs1, adjs2, hs_init, a0b, a1b, a2b, asumb, hsb, W_init, Wp, W0,
      W1, W2, W3, Wall);

  // 2) h0 -> hA (perm + lin)
  h0_kernel<<<dim3(8, Bn), dim3(256), 0, stream>>>(
      hsb, Wp, bn_init_mean, bn_init_var, bn_init_gamma, bn_init_beta, hApe,
      hAli);

  // 3) L0: reads hA -> writes hB + PA
  {
    LArgs La = {};
    La.Az[0] = a0b; La.Az[1] = a1b; La.Az[2] = a2b;
    La.Asum = asumb;
    La.Xh = hApe; La.hlin = hAli;
    La.Wl = Wall;
    La.bias = bvec; La.mean = bn_layer_mean; La.var = bn_layer_var;
    La.gamma = bn_layer_gamma; La.beta = bn_layer_beta;
    La.hperm_o = hBpe; La.hlin_o = hBli;
    La.Po[0] = PA0; La.Po[1] = PA1; La.Po[2] = PA2;
    layer_kernel<1><<<dim3(16, Bn), dim3(256), 0, stream>>>(La);
  }
  // 4) L1: reads hB, PA -> writes hA + PB
  {
    LArgs La = {};
    La.Az[0] = a0b; La.Az[1] = a1b; La.Az[2] = a2b;
    La.Asum = asumb;
    La.Xh = hBpe; La.hlin = hBli;
    La.XP[0] = PA0; La.XP[1] = PA1; La.XP[2] = PA2;
    La.Wl = Wall + 4 * 4096;
    La.bias = bvec + 64; La.mean = bn_layer_mean + 512;
    La.var = bn_layer_var + 512; La.gamma = bn_layer_gamma + 512;
    La.beta = bn_layer_beta + 512;
    La.hperm_o = hApe; La.hlin_o = hAli;
    La.Po[0] = PB0; La.Po[1] = PB1; La.Po[2] = PB2;
    layer_kernel<2><<<dim3(16, Bn), dim3(256), 0, stream>>>(La);
  }
  // 5) L2: reads hA, PB -> writes hB (h3 perm only)
  {
    LArgs La = {};
    La.Az[0] = a0b; La.Az[1] = a1b; La.Az[2] = a2b;
    La.Asum = asumb;
    La.Xh = hApe; La.hlin = hAli;
    La.XP[0] = PB0; La.XP[1] = PB1; La.XP[2] = PB2;
    La.Wl = Wall + 8 * 4096;
    La.bias = bvec + 128; La.mean = bn_layer_mean + 1024;
    La.var = bn_layer_var + 1024; La.gamma = bn_layer_gamma + 1024;
    La.beta = bn_layer_beta + 1024;
    La.hperm_o = hBpe; La.hlin_o = nullptr;
    La.Po[0] = nullptr; La.Po[1] = nullptr; La.Po[2] = nullptr;
    layer_kernel<2><<<dim3(16, Bn), dim3(256), 0, stream>>>(La);
  }

  // 6) head
  head_kernel<<<dim3(Bn), dim3(256), 0, stream>>>(
      hBpe, bn_graph_mean, bn_graph_var, bn_graph_gamma, bn_graph_beta, fc1_w,
      fc1_b, (float*)d_out);
}

// Round 10
// 86.597 us; speedup vs baseline: 2.2043x; 1.0682x over previous
//
#include <hip/hip_runtime.h>

typedef __attribute__((ext_vector_type(8))) short bf16x8;
typedef __attribute__((ext_vector_type(4))) float f32x4;
typedef __attribute__((ext_vector_type(8))) unsigned short u16x8;

constexpr int Bn = 16;
constexpr int Nn = 512;
constexpr int Fn = 64;
constexpr int Aout = 512;

static __device__ __forceinline__ unsigned short f2bf(float f) {
  union { float f; unsigned int u; } v; v.f = f;
  unsigned int r = v.u + 0x7fffu + ((v.u >> 16) & 1u);
  return (unsigned short)(r >> 16);
}
static __device__ __forceinline__ float bf2f(unsigned short u) {
  union { unsigned int u; float f; } v; v.u = ((unsigned int)u) << 16;
  return v.f;
}
static __device__ __forceinline__ unsigned int pk2(float a, float b) {
  union { float f; unsigned int u; } ua, ub; ua.f = a; ub.f = b;
  return ((ua.u + 0x8000u) >> 16) | ((ub.u + 0x8000u) & 0xFFFF0000u);
}

// B-perm (X/B-operand fragment layout), cols c, contraction k, K total:
//   frag = (c>>4)*(K/32) + (k>>5); off = frag*512 + ((c&15) + 16*((k>>3)&3))*8 + (k&7)

// ---------------------------------------------------------------------------
// prep (weights only now):
// [0,16): W_init -> B-perm (K=512); [16,40): W3/W0/W1/W2 per layer -> B-perm K=64
// ---------------------------------------------------------------------------
__launch_bounds__(256)
__global__ void prep_kernel(const float* __restrict__ Wi,
                            unsigned short* __restrict__ Wp,
                            const float* __restrict__ W0,
                            const float* __restrict__ W1,
                            const float* __restrict__ W2,
                            const float* __restrict__ W3,
                            unsigned short* __restrict__ Wall) {
  const int blk = blockIdx.x;
  if (blk < 16) {
    const int idx = blk * 256 + threadIdx.x;  // [0,4096)
    const int f = idx >> 6, o = idx & 63;
    const int k0 = o * 8;
    const size_t dst = ((size_t)((f >> 4) * 16 + (k0 >> 5)) << 9) +
                       (((f & 15) + 16 * ((k0 >> 3) & 3)) << 3);
    unsigned short w[8];
#pragma unroll
    for (int j = 0; j < 8; ++j) w[j] = f2bf(Wi[(size_t)(k0 + j) * Fn + f]);
    *(uint4*)(Wp + dst) = *(const uint4*)w;
  } else {
    const int r = blk - 16;
    const int mat = r >> 1;  // 0..11 = l*4 + m (m: W3,W0,W1,W2)
    const int l = mat >> 2, m = mat & 3;
    const int idx = (r & 1) * 256 + threadIdx.x;  // [0,512)
    const int co = idx >> 3, oct = idx & 7;
    const int k0 = oct * 8;
    const float* src = (m == 0 ? W3 : m == 1 ? W0 : m == 2 ? W1 : W2) + l * 4096;
    const size_t dst = (size_t)mat * 4096 +
                       ((size_t)((co >> 4) * 2 + (k0 >> 5)) << 9) +
                       (((co & 15) + 16 * ((k0 >> 3) & 3)) << 3);
    unsigned short w[8];
#pragma unroll
    for (int j = 0; j < 8; ++j) w[j] = f2bf(src[(k0 + j) * 64 + co]);
    *(uint4*)(Wall + dst) = *(const uint4*)w;
  }
}

// ---------------------------------------------------------------------------
// h0 kernel: h0 = relu(BN_init(hs @ Wi)); A = fp32 hs_init direct (pack in
// register), X = B-perm Wi. Outputs B-perm AND linear bf16.
// ---------------------------------------------------------------------------
__launch_bounds__(256, 1)
__global__ void h0_kernel(const float* __restrict__ hs,
                          const unsigned short* __restrict__ Wp,
                          const float* __restrict__ mean,
                          const float* __restrict__ var,
                          const float* __restrict__ gamma,
                          const float* __restrict__ beta,
                          unsigned short* __restrict__ operm,
                          unsigned short* __restrict__ olin) {
  const int b = blockIdx.y;
  const int R0 = blockIdx.x * 64;
  const int tid = threadIdx.x;
  const int w = tid >> 6, l = tid & 63;
  const int lr = l & 15, q = l >> 4;

  const float* Af = hs + ((size_t)b << 18) + (size_t)(R0 + w * 16 + lr) * 512 + q * 8;
  const unsigned short* Xf = Wp + l * 8;

  f32x4 acc[4] = {{0.f, 0.f, 0.f, 0.f}, {0.f, 0.f, 0.f, 0.f},
                  {0.f, 0.f, 0.f, 0.f}, {0.f, 0.f, 0.f, 0.f}};
  float4 ral[2][2];
  bf16x8 xb[2][4];
#define LD0(S_, T_)                                                       \
  {                                                                       \
    ral[S_][0] = *(const float4*)(Af + (T_)*32);                          \
    ral[S_][1] = *(const float4*)(Af + (T_)*32 + 4);                      \
    _Pragma("unroll") for (int c = 0; c < 4; ++c) xb[S_][c] =             \
        *(const bf16x8*)(Xf + c * 8192 + (T_)*512);                       \
  }
  LD0(0, 0)
#pragma unroll
  for (int t = 0; t < 16; ++t) {
    const int cur = t & 1;
    if (t + 1 < 16) LD0(cur ^ 1, t + 1)
    union { bf16x8 v; unsigned int u[4]; } cv;
    cv.u[0] = pk2(ral[cur][0].x, ral[cur][0].y);
    cv.u[1] = pk2(ral[cur][0].z, ral[cur][0].w);
    cv.u[2] = pk2(ral[cur][1].x, ral[cur][1].y);
    cv.u[3] = pk2(ral[cur][1].z, ral[cur][1].w);
#pragma unroll
    for (int c = 0; c < 4; ++c)
      acc[c] = __builtin_amdgcn_mfma_f32_16x16x32_bf16(cv.v, xb[cur][c], acc[c], 0, 0, 0);
  }
#undef LD0

  __shared__ __align__(16) unsigned short Tfn[64][72];  // [f][n]
  __shared__ __align__(16) unsigned short Tnf[64][72];  // [n][f]
  const int rbase = w * 16 + q * 4;
  float sc[4], mu[4], bt[4];
#pragma unroll
  for (int i = 0; i < 4; ++i) {
    int n = R0 + rbase + i;
    sc[i] = rsqrtf(var[n] + 1e-5f) * gamma[n];
    mu[i] = mean[n];
    bt[i] = beta[n];
  }
#pragma unroll
  for (int c = 0; c < 4; ++c) {
    ushort4 wv;
#pragma unroll
    for (int i = 0; i < 4; ++i) {
      float v = fmaxf(fmaf(acc[c][i] - mu[i], sc[i], bt[i]), 0.f);
      unsigned short uv = f2bf(v);
      ((unsigned short*)&wv)[i] = uv;
      Tnf[rbase + i][c * 16 + lr] = uv;
    }
    *(ushort4*)&Tfn[c * 16 + lr][rbase] = wv;
  }
  __syncthreads();
  {
    const int f = tid >> 2, oc = tid & 3;
    unsigned short* Ob = operm + ((size_t)b << 15);
#pragma unroll
    for (int p = 0; p < 2; ++p) {
      const int nl = oc * 8 + p * 32;
      const int nn = R0 + nl;
      const size_t dst = ((size_t)((f >> 4) * 16 + (nn >> 5)) << 9) +
                         (((f & 15) + 16 * ((nl >> 3) & 3)) << 3);
      *(uint4*)(Ob + dst) = *(const uint4*)&Tfn[f][nl];
    }
    const int n = tid >> 2;
    unsigned short* Ol = olin + ((size_t)b << 15) + (size_t)(R0 + n) * 64 + oc * 16;
    *(uint4*)Ol = *(const uint4*)&Tnf[n][oc * 16];
    *(uint4*)(Ol + 8) = *(const uint4*)&Tnf[n][oc * 16 + 8];
  }
}

// ---------------------------------------------------------------------------
// layer kernel: per block (32 n-rows, b):
//  phase A: P_z = a_z@h (+ asum@P_z_old if NSEG==2), fp32 adjacency read
//  directly; a_z packed to bf16 in-register; asum synthesized from the same
//  registers (fp32 add then pack). store P_z (B-perm).
//  phase B: h_tmp = h@W3 + sum_z P_z@W_z (MFMA K=64) -> bias+BN+ReLU ->
//  h_next (B-perm + linear).
// ---------------------------------------------------------------------------
struct LArgs {
  const float* Af0;
  const float* Af1;
  const float* Af2;
  const unsigned short* Xh;     // h B-perm
  const unsigned short* XP[3];  // P_old B-perm (NSEG==2)
  const unsigned short* hlin;   // h linear [n][f] bf16
  const unsigned short* Wl;     // 4 mats B-perm K=64: [W3,W0,W1,W2]
  const float *bias, *mean, *var, *gamma, *beta;
  unsigned short* hperm_o;
  unsigned short* hlin_o;  // null -> skip
  unsigned short* Po[3];   // null -> skip
};

template <int NSEG>
__launch_bounds__(256, 1)
__global__ void layer_kernel(LArgs La) {
  const int b = blockIdx.y;
  const int R0 = blockIdx.x * 32;
  const int tid = threadIdx.x;
  const int w = tid >> 6, l = tid & 63;
  const int lr = l & 15, q = l >> 4;
  const int nsub = (w & 1) * 16;
  const int cstart = (w >> 1) * 2;

  __shared__ __align__(16) unsigned short Tnf[3][32][72];  // [z][n][f]
  __shared__ __align__(16) unsigned short Tfn[3][64][40];  // [z][f][n]
  __shared__ __align__(16) unsigned short Hfn[64][40];     // h_next [f][n]
  __shared__ __align__(16) unsigned short Hnf[32][72];     // h_next [n][f]

  const size_t aoff = ((size_t)b << 18) + (size_t)(R0 + nsub + lr) * 512 + q * 8;
  const float* A0p = La.Af0 + aoff;
  const float* A1p = La.Af1 + aoff;
  const float* A2p = La.Af2 + aoff;
  const size_t xoff = ((size_t)b << 15) + (size_t)cstart * 8192 + l * 8;
  const unsigned short* Xhp = La.Xh + xoff;
  const unsigned short* XP0p = (NSEG == 2) ? La.XP[0] + xoff : Xhp;
  const unsigned short* XP1p = (NSEG == 2) ? La.XP[1] + xoff : Xhp;
  const unsigned short* XP2p = (NSEG == 2) ? La.XP[2] + xoff : Xhp;

  f32x4 acc[3][2];
#pragma unroll
  for (int z = 0; z < 3; ++z)
#pragma unroll
    for (int c = 0; c < 2; ++c) acc[z][c] = {0.f, 0.f, 0.f, 0.f};

  float4 ra[2][3][2];  // [set][z][half]
  bf16x8 rxh[2][2];
  bf16x8 rxp[2][3][2];

#define LOADRAW(S_, T_)                                                   \
  {                                                                       \
    ra[S_][0][0] = *(const float4*)(A0p + (T_)*32);                       \
    ra[S_][0][1] = *(const float4*)(A0p + (T_)*32 + 4);                   \
    ra[S_][1][0] = *(const float4*)(A1p + (T_)*32);                       \
    ra[S_][1][1] = *(const float4*)(A1p + (T_)*32 + 4);                   \
    ra[S_][2][0] = *(const float4*)(A2p + (T_)*32);                       \
    ra[S_][2][1] = *(const float4*)(A2p + (T_)*32 + 4);                   \
    rxh[S_][0] = *(const bf16x8*)(Xhp + (T_)*512);                        \
    rxh[S_][1] = *(const bf16x8*)(Xhp + 8192 + (T_)*512);                 \
    if (NSEG == 2) {                                                      \
      rxp[S_][0][0] = *(const bf16x8*)(XP0p + (T_)*512);                  \
      rxp[S_][0][1] = *(const bf16x8*)(XP0p + 8192 + (T_)*512);           \
      rxp[S_][1][0] = *(const bf16x8*)(XP1p + (T_)*512);                  \
      rxp[S_][1][1] = *(const bf16x8*)(XP1p + 8192 + (T_)*512);           \
      rxp[S_][2][0] = *(const bf16x8*)(XP2p + (T_)*512);                  \
      rxp[S_][2][1] = *(const bf16x8*)(XP2p + 8192 + (T_)*512);           \
    }                                                                     \
  }

  LOADRAW(0, 0)
#pragma unroll
  for (int t = 0; t < 16; ++t) {
    const int cur = t & 1;
    if (t + 1 < 16) LOADRAW(cur ^ 1, t + 1)
    bf16x8 azf[3];
#pragma unroll
    for (int z = 0; z < 3; ++z) {
      union { bf16x8 v; unsigned int u[4]; } cv;
      cv.u[0] = pk2(ra[cur][z][0].x, ra[cur][z][0].y);
      cv.u[1] = pk2(ra[cur][z][0].z, ra[cur][z][0].w);
      cv.u[2] = pk2(ra[cur][z][1].x, ra[cur][z][1].y);
      cv.u[3] = pk2(ra[cur][z][1].z, ra[cur][z][1].w);
      azf[z] = cv.v;
    }
    bf16x8 asumf;
    if (NSEG == 2) {
      float4 s0, s1;
      s0.x = ra[cur][0][0].x + ra[cur][1][0].x + ra[cur][2][0].x;
      s0.y = ra[cur][0][0].y + ra[cur][1][0].y + ra[cur][2][0].y;
      s0.z = ra[cur][0][0].z + ra[cur][1][0].z + ra[cur][2][0].z;
      s0.w = ra[cur][0][0].w + ra[cur][1][0].w + ra[cur][2][0].w;
      s1.x = ra[cur][0][1].x + ra[cur][1][1].x + ra[cur][2][1].x;
      s1.y = ra[cur][0][1].y + ra[cur][1][1].y + ra[cur][2][1].y;
      s1.z = ra[cur][0][1].z + ra[cur][1][1].z + ra[cur][2][1].z;
      s1.w = ra[cur][0][1].w + ra[cur][1][1].w + ra[cur][2][1].w;
      union { bf16x8 v; unsigned int u[4]; } cv;
      cv.u[0] = pk2(s0.x, s0.y);
      cv.u[1] = pk2(s0.z, s0.w);
      cv.u[2] = pk2(s1.x, s1.y);
      cv.u[3] = pk2(s1.z, s1.w);
      asumf = cv.v;
    }
#pragma unroll
    for (int z = 0; z < 3; ++z) {
#pragma unroll
      for (int c = 0; c < 2; ++c) {
        acc[z][c] = __builtin_amdgcn_mfma_f32_16x16x32_bf16(azf[z], rxh[cur][c],
                                                            acc[z][c], 0, 0, 0);
        if (NSEG == 2)
          acc[z][c] = __builtin_amdgcn_mfma_f32_16x16x32_bf16(
              asumf, rxp[cur][z][c], acc[z][c], 0, 0, 0);
      }
    }
  }
#undef LOADRAW

  // stage P_z tiles to LDS in both layouts
#pragma unroll
  for (int z = 0; z < 3; ++z) {
#pragma unroll
    for (int c = 0; c < 2; ++c) {
      const int f = (cstart + c) * 16 + lr;
      ushort4 wv;
#pragma unroll
      for (int i = 0; i < 4; ++i) {
        unsigned short uv = f2bf(acc[z][c][i]);
        ((unsigned short*)&wv)[i] = uv;
        Tnf[z][nsub + q * 4 + i][f] = uv;
      }
      *(ushort4*)&Tfn[z][f][nsub + q * 4] = wv;
    }
  }
  __syncthreads();

  // P_z global stores (B-perm)
  if (La.Po[0] != nullptr) {
    const int f = tid >> 2, oc = tid & 3;
    const int nl = oc * 8;
    const size_t dst = ((size_t)b << 15) +
                       ((size_t)((f >> 4) * 16 + (R0 >> 5)) << 9) +
                       (((f & 15) + 16 * ((nl >> 3) & 3)) << 3);
#pragma unroll
    for (int z = 0; z < 3; ++z)
      *(uint4*)(La.Po[z] + dst) = *(const uint4*)&Tfn[z][f][nl];
  }

  // phase B: h_tmp = h@W3 + sum_z P_z@W_z  (contraction over f=64)
  f32x4 acch[2] = {{0.f, 0.f, 0.f, 0.f}, {0.f, 0.f, 0.f, 0.f}};
#pragma unroll
  for (int m = 0; m < 4; ++m) {
#pragma unroll
    for (int ks = 0; ks < 2; ++ks) {
      bf16x8 af;
      if (m == 0)
        af = *(const bf16x8*)(La.hlin + ((size_t)b << 15) +
                              (size_t)(R0 + nsub + lr) * 64 + q * 8 + ks * 32);
      else
        af = *(const bf16x8*)&Tnf[m - 1][nsub + lr][q * 8 + ks * 32];
#pragma unroll
      for (int c = 0; c < 2; ++c) {
        const bf16x8 bf_ = *(const bf16x8*)(
            La.Wl + m * 4096 + ((size_t)((cstart + c) * 2 + ks) << 9) + l * 8);
        acch[c] =
            __builtin_amdgcn_mfma_f32_16x16x32_bf16(af, bf_, acch[c], 0, 0, 0);
      }
    }
  }
  __syncthreads();

  // epilogue: bias + BN + ReLU -> Hfn/Hnf
  {
    float sc[4], mu[4], bt[4];
#pragma unroll
    for (int i = 0; i < 4; ++i) {
      int n = R0 + nsub + q * 4 + i;
      sc[i] = rsqrtf(La.var[n] + 1e-5f) * La.gamma[n];
      mu[i] = La.mean[n];
      bt[i] = La.beta[n];
    }
#pragma unroll
    for (int c = 0; c < 2; ++c) {
      const int f = (cstart + c) * 16 + lr;
      const float bia = La.bias[f];
      ushort4 wv;
#pragma unroll
      for (int i = 0; i < 4; ++i) {
        float v = acch[c][i] + bia;
        v = fmaxf(fmaf(v - mu[i], sc[i], bt[i]), 0.f);
        unsigned short uv = f2bf(v);
        ((unsigned short*)&wv)[i] = uv;
        Hnf[nsub + q * 4 + i][f] = uv;
      }
      *(ushort4*)&Hfn[f][nsub + q * 4] = wv;
    }
  }
  __syncthreads();

  // h_next global stores
  {
    const int f = tid >> 2, oc = tid & 3;
    const int nl = oc * 8;
    const size_t dst = ((size_t)b << 15) +
                       ((size_t)((f >> 4) * 16 + (R0 >> 5)) << 9) +
                       (((f & 15) + 16 * ((nl >> 3) & 3)) << 3);
    *(uint4*)(La.hperm_o + dst) = *(const uint4*)&Hfn[f][nl];
    if (La.hlin_o != nullptr) {
      const int n = tid >> 3, oc8 = tid & 7;
      unsigned short* Ol =
          La.hlin_o + ((size_t)b << 15) + (size_t)(R0 + n) * 64 + oc8 * 8;
      *(uint4*)Ol = *(const uint4*)&Hnf[n][oc8 * 8];
    }
  }
}

// ---------------------------------------------------------------------------
// head: sum over n (B-perm h3) -> BN+ReLU -> FC(512) -> softmax. block per b.
// ---------------------------------------------------------------------------
__launch_bounds__(256)
__global__ void head_kernel(const unsigned short* __restrict__ h3p,
                            const float* __restrict__ gmean,
                            const float* __restrict__ gvar,
                            const float* __restrict__ ggamma,
                            const float* __restrict__ gbeta,
                            const float* __restrict__ fc_w,
                            const float* __restrict__ fc_b,
                            float* __restrict__ out) {
  const int b = blockIdx.x;
  const int t = threadIdx.x;
  __shared__ float part[256];
  __shared__ float gh[64];
  __shared__ float red[256];

  const int f = t >> 2, q = t & 3;
  const unsigned short* hp = h3p + ((size_t)b << 15);
  float s = 0.f;
#pragma unroll
  for (int m = 0; m < 16; ++m) {
    const int n = q * 128 + m * 8;
    const size_t off = ((size_t)((f >> 4) * 16 + (n >> 5)) << 9) +
                       (((f & 15) + 16 * ((n >> 3) & 3)) << 3);
    u16x8 v = *(const u16x8*)(hp + off);
#pragma unroll
    for (int e = 0; e < 8; ++e) s += bf2f((unsigned short)v[e]);
  }
  part[t] = s;
  __syncthreads();
  if (t < 64) {
    float sum = part[t * 4] + part[t * 4 + 1] + part[t * 4 + 2] + part[t * 4 + 3];
    float sc = rsqrtf(gvar[t] + 1e-5f) * ggamma[t];
    float v = fmaf(sum - gmean[t], sc, gbeta[t]);
    gh[t] = v > 0.f ? v : 0.f;
  }
  __syncthreads();

  float lg[2];
#pragma unroll
  for (int rep = 0; rep < 2; ++rep) {
    const int a = t + rep * 256;
    const float* __restrict__ wv = fc_w + (size_t)a * Fn;
    float acc = fc_b[a];
#pragma unroll 8
    for (int kk = 0; kk < 64; ++kk) acc = fmaf(gh[kk], wv[kk], acc);
    lg[rep] = acc;
  }
  red[t] = fmaxf(lg[0], lg[1]);
  __syncthreads();
  for (int off = 128; off > 0; off >>= 1) {
    if (t < off) red[t] = fmaxf(red[t], red[t + off]);
    __syncthreads();
  }
  const float mx = red[0];
  __syncthreads();
  const float e0 = __expf(lg[0] - mx), e1 = __expf(lg[1] - mx);
  red[t] = e0 + e1;
  __syncthreads();
  for (int off = 128; off > 0; off >>= 1) {
    if (t < off) red[t] += red[t + off];
    __syncthreads();
  }
  const float inv = 1.f / red[0];
  out[(size_t)b * Aout + t] = e0 * inv;
  out[(size_t)b * Aout + t + 256] = e1 * inv;
}

// ---------------------------------------------------------------------------
extern "C" void kernel_launch(void* const* d_in, const int* in_sizes, int n_in,
                              void* d_out, int out_size, void* d_ws,
                              size_t ws_size, hipStream_t stream) {
  (void)in_sizes; (void)n_in; (void)out_size; (void)ws_size;
  const float* hs_init = (const float*)d_in[0];
  const float* adjs0 = (const float*)d_in[1];
  const float* adjs1 = (const float*)d_in[2];
  const float* adjs2 = (const float*)d_in[3];
  const float* W_init = (const float*)d_in[4];
  const float* W0 = (const float*)d_in[5];
  const float* W1 = (const float*)d_in[6];
  const float* W2 = (const float*)d_in[7];
  const float* W3 = (const float*)d_in[8];
  const float* bvec = (const float*)d_in[9];
  const float* fc1_w = (const float*)d_in[10];
  const float* fc1_b = (const float*)d_in[11];
  const float* bn_init_mean = (const float*)d_in[12];
  const float* bn_init_var = (const float*)d_in[13];
  const float* bn_init_gamma = (const float*)d_in[14];
  const float* bn_init_beta = (const float*)d_in[15];
  const float* bn_layer_mean = (const float*)d_in[16];
  const float* bn_layer_var = (const float*)d_in[17];
  const float* bn_layer_gamma = (const float*)d_in[18];
  const float* bn_layer_beta = (const float*)d_in[19];
  const float* bn_graph_mean = (const float*)d_in[20];
  const float* bn_graph_var = (const float*)d_in[21];
  const float* bn_graph_gamma = (const float*)d_in[22];
  const float* bn_graph_beta = (const float*)d_in[23];

  const size_t NF = (size_t)Bn * Fn * Nn;  // 524,288

  unsigned short* wsu = (unsigned short*)d_ws;
  unsigned short* Wp = wsu;            // 32768
  unsigned short* Wall = Wp + 32768;   // 49152
  unsigned short* hApe = Wall + 49152;
  unsigned short* hBpe = hApe + NF;
  unsigned short* hAli = hBpe + NF;
  unsigned short* hBli = hAli + NF;
  unsigned short* PA0 = hBli + NF;
  unsigned short* PA1 = PA0 + NF;
  unsigned short* PA2 = PA1 + NF;
  unsigned short* PB0 = PA2 + NF;
  unsigned short* PB1 = PB0 + NF;
  unsigned short* PB2 = PB1 + NF;

  // 1) prep (weights only)
  prep_kernel<<<dim3(40), dim3(256), 0, stream>>>(W_init, Wp, W0, W1, W2, W3,
                                                  Wall);

  // 2) h0 -> hA (perm + lin), fp32 hs_init direct
  h0_kernel<<<dim3(8, Bn), dim3(256), 0, stream>>>(
      hs_init, Wp, bn_init_mean, bn_init_var, bn_init_gamma, bn_init_beta,
      hApe, hAli);

  // 3) L0: reads hA -> writes hB + PA
  {
    LArgs La = {};
    La.Af0 = adjs0; La.Af1 = adjs1; La.Af2 = adjs2;
    La.Xh = hApe; La.hlin = hAli;
    La.Wl = Wall;
    La.bias = bvec; La.mean = bn_layer_mean; La.var = bn_layer_var;
    La.gamma = bn_layer_gamma; La.beta = bn_layer_beta;
    La.hperm_o = hBpe; La.hlin_o = hBli;
    La.Po[0] = PA0; La.Po[1] = PA1; La.Po[2] = PA2;
    layer_kernel<1><<<dim3(16, Bn), dim3(256), 0, stream>>>(La);
  }
  // 4) L1: reads hB, PA -> writes hA + PB
  {
    LArgs La = {};
    La.Af0 = adjs0; La.Af1 = adjs1; La.Af2 = adjs2;
    La.Xh = hBpe; La.hlin = hBli;
    La.XP[0] = PA0; La.XP[1] = PA1; La.XP[2] = PA2;
    La.Wl = Wall + 4 * 4096;
    La.bias = bvec + 64; La.mean = bn_layer_mean + 512;
    La.var = bn_layer_var + 512; La.gamma = bn_layer_gamma + 512;
    La.beta = bn_layer_beta + 512;
    La.hperm_o = hApe; La.hlin_o = hAli;
    La.Po[0] = PB0; La.Po[1] = PB1; La.Po[2] = PB2;
    layer_kernel<2><<<dim3(16, Bn), dim3(256), 0, stream>>>(La);
  }
  // 5) L2: reads hA, PB -> writes hB (h3 perm only)
  {
    LArgs La = {};
    La.Af0 = adjs0; La.Af1 = adjs1; La.Af2 = adjs2;
    La.Xh = hApe; La.hlin = hAli;
    La.XP[0] = PB0; La.XP[1] = PB1; La.XP[2] = PB2;
    La.Wl = Wall + 8 * 4096;
    La.bias = bvec + 128; La.mean = bn_layer_mean + 1024;
    La.var = bn_layer_var + 1024; La.gamma = bn_layer_gamma + 1024;
    La.beta = bn_layer_beta + 1024;
    La.hperm_o = hBpe; La.hlin_o = nullptr;
    La.Po[0] = nullptr; La.Po[1] = nullptr; La.Po[2] = nullptr;
    layer_kernel<2><<<dim3(16, Bn), dim3(256), 0, stream>>>(La);
  }

  // 6) head
  head_kernel<<<dim3(Bn), dim3(256), 0, stream>>>(
      hBpe, bn_graph_mean, bn_graph_var, bn_graph_gamma, bn_graph_beta, fc1_w,
      fc1_b, (float*)d_out);
}

// Round 11
// 86.103 us; speedup vs baseline: 2.2170x; 1.0057x over previous
//
#include <hip/hip_runtime.h>

typedef __attribute__((ext_vector_type(8))) short bf16x8;
typedef __attribute__((ext_vector_type(4))) float f32x4;
typedef __attribute__((ext_vector_type(8))) unsigned short u16x8;

constexpr int Bn = 16;
constexpr int Nn = 512;
constexpr int Fn = 64;
constexpr int Aout = 512;

static __device__ __forceinline__ unsigned short f2bf(float f) {
  union { float f; unsigned int u; } v; v.f = f;
  unsigned int r = v.u + 0x7fffu + ((v.u >> 16) & 1u);
  return (unsigned short)(r >> 16);
}
static __device__ __forceinline__ float bf2f(unsigned short u) {
  union { unsigned int u; float f; } v; v.u = ((unsigned int)u) << 16;
  return v.f;
}
static __device__ __forceinline__ unsigned int pk2(float a, float b) {
  union { float f; unsigned int u; } ua, ub; ua.f = a; ub.f = b;
  return ((ua.u + 0x8000u) >> 16) | ((ub.u + 0x8000u) & 0xFFFF0000u);
}
// async global(fp32,16B/lane) -> LDS. lds dest must be wave-uniform base.
static __device__ __forceinline__ void gload_lds16(const float* g, float* l) {
  __builtin_amdgcn_global_load_lds(
      (const __attribute__((address_space(1))) void*)g,
      (__attribute__((address_space(3))) void*)l, 16, 0, 0);
}

// B-perm (X/B-operand fragment layout), cols c, contraction k, K total:
//   frag = (c>>4)*(K/32) + (k>>5); off = frag*512 + ((c&15) + 16*((k>>3)&3))*8 + (k&7)

// ---------------------------------------------------------------------------
// prep (weights only):
// [0,16): W_init -> B-perm (K=512); [16,40): W3/W0/W1/W2 per layer -> B-perm K=64
// ---------------------------------------------------------------------------
__launch_bounds__(256)
__global__ void prep_kernel(const float* __restrict__ Wi,
                            unsigned short* __restrict__ Wp,
                            const float* __restrict__ W0,
                            const float* __restrict__ W1,
                            const float* __restrict__ W2,
                            const float* __restrict__ W3,
                            unsigned short* __restrict__ Wall) {
  const int blk = blockIdx.x;
  if (blk < 16) {
    const int idx = blk * 256 + threadIdx.x;  // [0,4096)
    const int f = idx >> 6, o = idx & 63;
    const int k0 = o * 8;
    const size_t dst = ((size_t)((f >> 4) * 16 + (k0 >> 5)) << 9) +
                       (((f & 15) + 16 * ((k0 >> 3) & 3)) << 3);
    unsigned short w[8];
#pragma unroll
    for (int j = 0; j < 8; ++j) w[j] = f2bf(Wi[(size_t)(k0 + j) * Fn + f]);
    *(uint4*)(Wp + dst) = *(const uint4*)w;
  } else {
    const int r = blk - 16;
    const int mat = r >> 1;  // 0..11 = l*4 + m (m: W3,W0,W1,W2)
    const int l = mat >> 2, m = mat & 3;
    const int idx = (r & 1) * 256 + threadIdx.x;  // [0,512)
    const int co = idx >> 3, oct = idx & 7;
    const int k0 = oct * 8;
    const float* src = (m == 0 ? W3 : m == 1 ? W0 : m == 2 ? W1 : W2) + l * 4096;
    const size_t dst = (size_t)mat * 4096 +
                       ((size_t)((co >> 4) * 2 + (k0 >> 5)) << 9) +
                       (((co & 15) + 16 * ((k0 >> 3) & 3)) << 3);
    unsigned short w[8];
#pragma unroll
    for (int j = 0; j < 8; ++j) w[j] = f2bf(src[(k0 + j) * 64 + co]);
    *(uint4*)(Wall + dst) = *(const uint4*)w;
  }
}

// ---------------------------------------------------------------------------
// h0 kernel: h0 = relu(BN_init(hs @ Wi)); A = fp32 hs_init direct (pack in
// register), X = B-perm Wi. Outputs B-perm AND linear bf16.
// ---------------------------------------------------------------------------
__launch_bounds__(256, 1)
__global__ void h0_kernel(const float* __restrict__ hs,
                          const unsigned short* __restrict__ Wp,
                          const float* __restrict__ mean,
                          const float* __restrict__ var,
                          const float* __restrict__ gamma,
                          const float* __restrict__ beta,
                          unsigned short* __restrict__ operm,
                          unsigned short* __restrict__ olin) {
  const int b = blockIdx.y;
  const int R0 = blockIdx.x * 64;
  const int tid = threadIdx.x;
  const int w = tid >> 6, l = tid & 63;
  const int lr = l & 15, q = l >> 4;

  const float* Af = hs + ((size_t)b << 18) + (size_t)(R0 + w * 16 + lr) * 512 + q * 8;
  const unsigned short* Xf = Wp + l * 8;

  f32x4 acc[4] = {{0.f, 0.f, 0.f, 0.f}, {0.f, 0.f, 0.f, 0.f},
                  {0.f, 0.f, 0.f, 0.f}, {0.f, 0.f, 0.f, 0.f}};
  float4 ral[2][2];
  bf16x8 xb[2][4];
#define LD0(S_, T_)                                                       \
  {                                                                       \
    ral[S_][0] = *(const float4*)(Af + (T_)*32);                          \
    ral[S_][1] = *(const float4*)(Af + (T_)*32 + 4);                      \
    _Pragma("unroll") for (int c = 0; c < 4; ++c) xb[S_][c] =             \
        *(const bf16x8*)(Xf + c * 8192 + (T_)*512);                       \
  }
  LD0(0, 0)
#pragma unroll
  for (int t = 0; t < 16; ++t) {
    const int cur = t & 1;
    if (t + 1 < 16) LD0(cur ^ 1, t + 1)
    union { bf16x8 v; unsigned int u[4]; } cv;
    cv.u[0] = pk2(ral[cur][0].x, ral[cur][0].y);
    cv.u[1] = pk2(ral[cur][0].z, ral[cur][0].w);
    cv.u[2] = pk2(ral[cur][1].x, ral[cur][1].y);
    cv.u[3] = pk2(ral[cur][1].z, ral[cur][1].w);
#pragma unroll
    for (int c = 0; c < 4; ++c)
      acc[c] = __builtin_amdgcn_mfma_f32_16x16x32_bf16(cv.v, xb[cur][c], acc[c], 0, 0, 0);
  }
#undef LD0

  __shared__ __align__(16) unsigned short Tfn[64][72];  // [f][n]
  __shared__ __align__(16) unsigned short Tnf[64][72];  // [n][f]
  const int rbase = w * 16 + q * 4;
  float sc[4], mu[4], bt[4];
#pragma unroll
  for (int i = 0; i < 4; ++i) {
    int n = R0 + rbase + i;
    sc[i] = rsqrtf(var[n] + 1e-5f) * gamma[n];
    mu[i] = mean[n];
    bt[i] = beta[n];
  }
#pragma unroll
  for (int c = 0; c < 4; ++c) {
    ushort4 wv;
#pragma unroll
    for (int i = 0; i < 4; ++i) {
      float v = fmaxf(fmaf(acc[c][i] - mu[i], sc[i], bt[i]), 0.f);
      unsigned short uv = f2bf(v);
      ((unsigned short*)&wv)[i] = uv;
      Tnf[rbase + i][c * 16 + lr] = uv;
    }
    *(ushort4*)&Tfn[c * 16 + lr][rbase] = wv;
  }
  __syncthreads();
  {
    const int f = tid >> 2, oc = tid & 3;
    unsigned short* Ob = operm + ((size_t)b << 15);
#pragma unroll
    for (int p = 0; p < 2; ++p) {
      const int nl = oc * 8 + p * 32;
      const int nn = R0 + nl;
      const size_t dst = ((size_t)((f >> 4) * 16 + (nn >> 5)) << 9) +
                         (((f & 15) + 16 * ((nl >> 3) & 3)) << 3);
      *(uint4*)(Ob + dst) = *(const uint4*)&Tfn[f][nl];
    }
    const int n = tid >> 2;
    unsigned short* Ol = olin + ((size_t)b << 15) + (size_t)(R0 + n) * 64 + oc * 16;
    *(uint4*)Ol = *(const uint4*)&Tnf[n][oc * 16];
    *(uint4*)(Ol + 8) = *(const uint4*)&Tnf[n][oc * 16 + 8];
  }
}

// ---------------------------------------------------------------------------
// layer kernel (v11): per block (32 n-rows, b):
//  phase A: P_z = a_z@h (+ asum@P_z_old if NSEG==2); fp32 adjacency staged
//  via global_load_lds double-buffer (XOR-preswizzled source, XOR on read);
//  asum synthesized in-register. X (h/P B-perm) = VGPR depth-2 prefetch.
//  phase B: h_tmp = h@W3 + sum_z P_z@W_z -> bias+BN+ReLU -> h_next.
//  Grid: flat 256, XCD-swizzled so all n-tiles of a batch share one XCD L2.
// ---------------------------------------------------------------------------
struct LArgs {
  const float* Af0;
  const float* Af1;
  const float* Af2;
  const unsigned short* Xh;     // h B-perm
  const unsigned short* XP[3];  // P_old B-perm (NSEG==2)
  const unsigned short* hlin;   // h linear [n][f] bf16
  const unsigned short* Wl;     // 4 mats B-perm K=64: [W3,W0,W1,W2]
  const float *bias, *mean, *var, *gamma, *beta;
  unsigned short* hperm_o;
  unsigned short* hlin_o;  // null -> skip
  unsigned short* Po[3];   // null -> skip
};

template <int NSEG>
__launch_bounds__(256, 1)
__global__ void layer_kernel(LArgs La) {
  // XCD swizzle: flat%8 = XCD; b = (flat&7) + 8*(flat>>7); ntile = (flat>>3)&15
  const int flat = blockIdx.x;
  const int b = (flat & 7) + ((flat >> 7) << 3);
  const int R0 = ((flat >> 3) & 15) * 32;
  const int tid = threadIdx.x;
  const int w = tid >> 6, l = tid & 63;
  const int lr = l & 15, q = l >> 4;
  const int nsub = (w & 1) * 16;
  const int cstart = (w >> 1) * 2;

  __shared__ __align__(16) float Asg[2][3][32][32];        // 24 KB A staging
  __shared__ __align__(16) unsigned short Tnf[3][32][72];  // [z][n][f]
  __shared__ __align__(16) unsigned short Tfn[3][64][40];  // [z][f][n]
  __shared__ __align__(16) unsigned short Hfn[64][40];     // h_next [f][n]
  __shared__ __align__(16) unsigned short Hnf[32][72];     // h_next [n][f]

  // staging lane constants: slot (srow, schunk) holds global chunk schunk^(srow&7)
  const int srow = tid >> 3;
  const int gchunk = (tid & 7) ^ (srow & 7);
  const size_t abase = ((size_t)b << 18) + (size_t)(R0 + srow) * 512 + gchunk * 4;
  const float* As0 = La.Af0 + abase;
  const float* As1 = La.Af1 + abase;
  const float* As2 = La.Af2 + abase;
  const int wv8 = w * 8;

  const size_t xoff = ((size_t)b << 15) + (size_t)cstart * 8192 + l * 8;
  const unsigned short* Xhp = La.Xh + xoff;
  const unsigned short* XP0p = (NSEG == 2) ? La.XP[0] + xoff : Xhp;
  const unsigned short* XP1p = (NSEG == 2) ? La.XP[1] + xoff : Xhp;
  const unsigned short* XP2p = (NSEG == 2) ? La.XP[2] + xoff : Xhp;

  f32x4 acc[3][2];
#pragma unroll
  for (int z = 0; z < 3; ++z)
#pragma unroll
    for (int c = 0; c < 2; ++c) acc[z][c] = {0.f, 0.f, 0.f, 0.f};

  bf16x8 rxh[2][2];
  bf16x8 rxp[2][3][2];

#define STAGE(BB, T)                                                     \
  {                                                                      \
    gload_lds16(As0 + (T)*32, &Asg[BB][0][wv8][0]);                      \
    gload_lds16(As1 + (T)*32, &Asg[BB][1][wv8][0]);                      \
    gload_lds16(As2 + (T)*32, &Asg[BB][2][wv8][0]);                      \
  }
#define LOADX(S_, T_)                                                    \
  {                                                                      \
    rxh[S_][0] = *(const bf16x8*)(Xhp + (T_)*512);                       \
    rxh[S_][1] = *(const bf16x8*)(Xhp + 8192 + (T_)*512);                \
    if (NSEG == 2) {                                                     \
      rxp[S_][0][0] = *(const bf16x8*)(XP0p + (T_)*512);                 \
      rxp[S_][0][1] = *(const bf16x8*)(XP0p + 8192 + (T_)*512);          \
      rxp[S_][1][0] = *(const bf16x8*)(XP1p + (T_)*512);                 \
      rxp[S_][1][1] = *(const bf16x8*)(XP1p + 8192 + (T_)*512);          \
      rxp[S_][2][0] = *(const bf16x8*)(XP2p + (T_)*512);                 \
      rxp[S_][2][1] = *(const bf16x8*)(XP2p + 8192 + (T_)*512);          \
    }                                                                    \
  }

  STAGE(0, 0)
  LOADX(0, 0)
  __syncthreads();  // Asg[0] ready (vmcnt drained by barrier semantics)

  const int r_ = nsub + lr;
  const int xr = r_ & 7;
  const int c0 = ((2 * q) ^ xr) << 2;      // fp32 col of k[q*8..q*8+3]
  const int c1 = ((2 * q + 1) ^ xr) << 2;  // fp32 col of k[q*8+4..q*8+7]

#pragma unroll
  for (int t = 0; t < 16; ++t) {
    const int cur = t & 1;
    if (t + 1 < 16) {
      STAGE(cur ^ 1, t + 1)
      LOADX(cur ^ 1, t + 1)
    }
    float4 fa[3], fb[3];
#pragma unroll
    for (int z = 0; z < 3; ++z) {
      fa[z] = *(const float4*)&Asg[cur][z][r_][c0];
      fb[z] = *(const float4*)&Asg[cur][z][r_][c1];
    }
    bf16x8 azf[3];
#pragma unroll
    for (int z = 0; z < 3; ++z) {
      union { bf16x8 v; unsigned int u[4]; } cv;
      cv.u[0] = pk2(fa[z].x, fa[z].y);
      cv.u[1] = pk2(fa[z].z, fa[z].w);
      cv.u[2] = pk2(fb[z].x, fb[z].y);
      cv.u[3] = pk2(fb[z].z, fb[z].w);
      azf[z] = cv.v;
    }
    bf16x8 asumf;
    if (NSEG == 2) {
      union { bf16x8 v; unsigned int u[4]; } cv;
      cv.u[0] = pk2(fa[0].x + fa[1].x + fa[2].x, fa[0].y + fa[1].y + fa[2].y);
      cv.u[1] = pk2(fa[0].z + fa[1].z + fa[2].z, fa[0].w + fa[1].w + fa[2].w);
      cv.u[2] = pk2(fb[0].x + fb[1].x + fb[2].x, fb[0].y + fb[1].y + fb[2].y);
      cv.u[3] = pk2(fb[0].z + fb[1].z + fb[2].z, fb[0].w + fb[1].w + fb[2].w);
      asumf = cv.v;
    }
#pragma unroll
    for (int z = 0; z < 3; ++z) {
#pragma unroll
      for (int c = 0; c < 2; ++c) {
        acc[z][c] = __builtin_amdgcn_mfma_f32_16x16x32_bf16(azf[z], rxh[cur][c],
                                                            acc[z][c], 0, 0, 0);
        if (NSEG == 2)
          acc[z][c] = __builtin_amdgcn_mfma_f32_16x16x32_bf16(
              asumf, rxp[cur][z][c], acc[z][c], 0, 0, 0);
      }
    }
    __syncthreads();  // next buf staged; all waves done with Asg[cur]
  }
#undef STAGE
#undef LOADX

  // stage P_z tiles to LDS in both layouts
#pragma unroll
  for (int z = 0; z < 3; ++z) {
#pragma unroll
    for (int c = 0; c < 2; ++c) {
      const int f = (cstart + c) * 16 + lr;
      ushort4 wv;
#pragma unroll
      for (int i = 0; i < 4; ++i) {
        unsigned short uv = f2bf(acc[z][c][i]);
        ((unsigned short*)&wv)[i] = uv;
        Tnf[z][nsub + q * 4 + i][f] = uv;
      }
      *(ushort4*)&Tfn[z][f][nsub + q * 4] = wv;
    }
  }
  __syncthreads();

  // P_z global stores (B-perm)
  if (La.Po[0] != nullptr) {
    const int f = tid >> 2, oc = tid & 3;
    const int nl = oc * 8;
    const size_t dst = ((size_t)b << 15) +
                       ((size_t)((f >> 4) * 16 + (R0 >> 5)) << 9) +
                       (((f & 15) + 16 * ((nl >> 3) & 3)) << 3);
#pragma unroll
    for (int z = 0; z < 3; ++z)
      *(uint4*)(La.Po[z] + dst) = *(const uint4*)&Tfn[z][f][nl];
  }

  // phase B: h_tmp = h@W3 + sum_z P_z@W_z  (contraction over f=64)
  f32x4 acch[2] = {{0.f, 0.f, 0.f, 0.f}, {0.f, 0.f, 0.f, 0.f}};
#pragma unroll
  for (int m = 0; m < 4; ++m) {
#pragma unroll
    for (int ks = 0; ks < 2; ++ks) {
      bf16x8 af;
      if (m == 0)
        af = *(const bf16x8*)(La.hlin + ((size_t)b << 15) +
                              (size_t)(R0 + nsub + lr) * 64 + q * 8 + ks * 32);
      else
        af = *(const bf16x8*)&Tnf[m - 1][nsub + lr][q * 8 + ks * 32];
#pragma unroll
      for (int c = 0; c < 2; ++c) {
        const bf16x8 bf_ = *(const bf16x8*)(
            La.Wl + m * 4096 + ((size_t)((cstart + c) * 2 + ks) << 9) + l * 8);
        acch[c] =
            __builtin_amdgcn_mfma_f32_16x16x32_bf16(af, bf_, acch[c], 0, 0, 0);
      }
    }
  }
  __syncthreads();

  // epilogue: bias + BN + ReLU -> Hfn/Hnf
  {
    float sc[4], mu[4], bt[4];
#pragma unroll
    for (int i = 0; i < 4; ++i) {
      int n = R0 + nsub + q * 4 + i;
      sc[i] = rsqrtf(La.var[n] + 1e-5f) * La.gamma[n];
      mu[i] = La.mean[n];
      bt[i] = La.beta[n];
    }
#pragma unroll
    for (int c = 0; c < 2; ++c) {
      const int f = (cstart + c) * 16 + lr;
      const float bia = La.bias[f];
      ushort4 wv;
#pragma unroll
      for (int i = 0; i < 4; ++i) {
        float v = acch[c][i] + bia;
        v = fmaxf(fmaf(v - mu[i], sc[i], bt[i]), 0.f);
        unsigned short uv = f2bf(v);
        ((unsigned short*)&wv)[i] = uv;
        Hnf[nsub + q * 4 + i][f] = uv;
      }
      *(ushort4*)&Hfn[f][nsub + q * 4] = wv;
    }
  }
  __syncthreads();

  // h_next global stores
  {
    const int f = tid >> 2, oc = tid & 3;
    const int nl = oc * 8;
    const size_t dst = ((size_t)b << 15) +
                       ((size_t)((f >> 4) * 16 + (R0 >> 5)) << 9) +
                       (((f & 15) + 16 * ((nl >> 3) & 3)) << 3);
    *(uint4*)(La.hperm_o + dst) = *(const uint4*)&Hfn[f][nl];
    if (La.hlin_o != nullptr) {
      const int n = tid >> 3, oc8 = tid & 7;
      unsigned short* Ol =
          La.hlin_o + ((size_t)b << 15) + (size_t)(R0 + n) * 64 + oc8 * 8;
      *(uint4*)Ol = *(const uint4*)&Hnf[n][oc8 * 8];
    }
  }
}

// ---------------------------------------------------------------------------
// head: sum over n (B-perm h3) -> BN+ReLU -> FC(512) -> softmax. block per b.
// ---------------------------------------------------------------------------
__launch_bounds__(256)
__global__ void head_kernel(const unsigned short* __restrict__ h3p,
                            const float* __restrict__ gmean,
                            const float* __restrict__ gvar,
                            const float* __restrict__ ggamma,
                            const float* __restrict__ gbeta,
                            const float* __restrict__ fc_w,
                            const float* __restrict__ fc_b,
                            float* __restrict__ out) {
  const int b = blockIdx.x;
  const int t = threadIdx.x;
  __shared__ float part[256];
  __shared__ float gh[64];
  __shared__ float red[256];

  const int f = t >> 2, q = t & 3;
  const unsigned short* hp = h3p + ((size_t)b << 15);
  float s = 0.f;
#pragma unroll
  for (int m = 0; m < 16; ++m) {
    const int n = q * 128 + m * 8;
    const size_t off = ((size_t)((f >> 4) * 16 + (n >> 5)) << 9) +
                       (((f & 15) + 16 * ((n >> 3) & 3)) << 3);
    u16x8 v = *(const u16x8*)(hp + off);
#pragma unroll
    for (int e = 0; e < 8; ++e) s += bf2f((unsigned short)v[e]);
  }
  part[t] = s;
  __syncthreads();
  if (t < 64) {
    float sum = part[t * 4] + part[t * 4 + 1] + part[t * 4 + 2] + part[t * 4 + 3];
    float sc = rsqrtf(gvar[t] + 1e-5f) * ggamma[t];
    float v = fmaf(sum - gmean[t], sc, gbeta[t]);
    gh[t] = v > 0.f ? v : 0.f;
  }
  __syncthreads();

  float lg[2];
#pragma unroll
  for (int rep = 0; rep < 2; ++rep) {
    const int a = t + rep * 256;
    const float* __restrict__ wv = fc_w + (size_t)a * Fn;
    float acc = fc_b[a];
#pragma unroll 8
    for (int kk = 0; kk < 64; ++kk) acc = fmaf(gh[kk], wv[kk], acc);
    lg[rep] = acc;
  }
  red[t] = fmaxf(lg[0], lg[1]);
  __syncthreads();
  for (int off = 128; off > 0; off >>= 1) {
    if (t < off) red[t] = fmaxf(red[t], red[t + off]);
    __syncthreads();
  }
  const float mx = red[0];
  __syncthreads();
  const float e0 = __expf(lg[0] - mx), e1 = __expf(lg[1] - mx);
  red[t] = e0 + e1;
  __syncthreads();
  for (int off = 128; off > 0; off >>= 1) {
    if (t < off) red[t] += red[t + off];
    __syncthreads();
  }
  const float inv = 1.f / red[0];
  out[(size_t)b * Aout + t] = e0 * inv;
  out[(size_t)b * Aout + t + 256] = e1 * inv;
}

// ---------------------------------------------------------------------------
extern "C" void kernel_launch(void* const* d_in, const int* in_sizes, int n_in,
                              void* d_out, int out_size, void* d_ws,
                              size_t ws_size, hipStream_t stream) {
  (void)in_sizes; (void)n_in; (void)out_size; (void)ws_size;
  const float* hs_init = (const float*)d_in[0];
  const float* adjs0 = (const float*)d_in[1];
  const float* adjs1 = (const float*)d_in[2];
  const float* adjs2 = (const float*)d_in[3];
  const float* W_init = (const float*)d_in[4];
  const float* W0 = (const float*)d_in[5];
  const float* W1 = (const float*)d_in[6];
  const float* W2 = (const float*)d_in[7];
  const float* W3 = (const float*)d_in[8];
  const float* bvec = (const float*)d_in[9];
  const float* fc1_w = (const float*)d_in[10];
  const float* fc1_b = (const float*)d_in[11];
  const float* bn_init_mean = (const float*)d_in[12];
  const float* bn_init_var = (const float*)d_in[13];
  const float* bn_init_gamma = (const float*)d_in[14];
  const float* bn_init_beta = (const float*)d_in[15];
  const float* bn_layer_mean = (const float*)d_in[16];
  const float* bn_layer_var = (const float*)d_in[17];
  const float* bn_layer_gamma = (const float*)d_in[18];
  const float* bn_layer_beta = (const float*)d_in[19];
  const float* bn_graph_mean = (const float*)d_in[20];
  const float* bn_graph_var = (const float*)d_in[21];
  const float* bn_graph_gamma = (const float*)d_in[22];
  const float* bn_graph_beta = (const float*)d_in[23];

  const size_t NF = (size_t)Bn * Fn * Nn;  // 524,288

  unsigned short* wsu = (unsigned short*)d_ws;
  unsigned short* Wp = wsu;            // 32768
  unsigned short* Wall = Wp + 32768;   // 49152
  unsigned short* hApe = Wall + 49152;
  unsigned short* hBpe = hApe + NF;
  unsigned short* hAli = hBpe + NF;
  unsigned short* hBli = hAli + NF;
  unsigned short* PA0 = hBli + NF;
  unsigned short* PA1 = PA0 + NF;
  unsigned short* PA2 = PA1 + NF;
  unsigned short* PB0 = PA2 + NF;
  unsigned short* PB1 = PB0 + NF;
  unsigned short* PB2 = PB1 + NF;

  // 1) prep (weights only)
  prep_kernel<<<dim3(40), dim3(256), 0, stream>>>(W_init, Wp, W0, W1, W2, W3,
                                                  Wall);

  // 2) h0 -> hA (perm + lin), fp32 hs_init direct
  h0_kernel<<<dim3(8, Bn), dim3(256), 0, stream>>>(
      hs_init, Wp, bn_init_mean, bn_init_var, bn_init_gamma, bn_init_beta,
      hApe, hAli);

  // 3) L0: reads hA -> writes hB + PA
  {
    LArgs La = {};
    La.Af0 = adjs0; La.Af1 = adjs1; La.Af2 = adjs2;
    La.Xh = hApe; La.hlin = hAli;
    La.Wl = Wall;
    La.bias = bvec; La.mean = bn_layer_mean; La.var = bn_layer_var;
    La.gamma = bn_layer_gamma; La.beta = bn_layer_beta;
    La.hperm_o = hBpe; La.hlin_o = hBli;
    La.Po[0] = PA0; La.Po[1] = PA1; La.Po[2] = PA2;
    layer_kernel<1><<<dim3(256), dim3(256), 0, stream>>>(La);
  }
  // 4) L1: reads hB, PA -> writes hA + PB
  {
    LArgs La = {};
    La.Af0 = adjs0; La.Af1 = adjs1; La.Af2 = adjs2;
    La.Xh = hBpe; La.hlin = hBli;
    La.XP[0] = PA0; La.XP[1] = PA1; La.XP[2] = PA2;
    La.Wl = Wall + 4 * 4096;
    La.bias = bvec + 64; La.mean = bn_layer_mean + 512;
    La.var = bn_layer_var + 512; La.gamma = bn_layer_gamma + 512;
    La.beta = bn_layer_beta + 512;
    La.hperm_o = hApe; La.hlin_o = hAli;
    La.Po[0] = PB0; La.Po[1] = PB1; La.Po[2] = PB2;
    layer_kernel<2><<<dim3(256), dim3(256), 0, stream>>>(La);
  }
  // 5) L2: reads hA, PB -> writes hB (h3 perm only)
  {
    LArgs La = {};
    La.Af0 = adjs0; La.Af1 = adjs1; La.Af2 = adjs2;
    La.Xh = hApe; La.hlin = hAli;
    La.XP[0] = PB0; La.XP[1] = PB1; La.XP[2] = PB2;
    La.Wl = Wall + 8 * 4096;
    La.bias = bvec + 128; La.mean = bn_layer_mean + 1024;
    La.var = bn_layer_var + 1024; La.gamma = bn_layer_gamma + 1024;
    La.beta = bn_layer_beta + 1024;
    La.hperm_o = hBpe; La.hlin_o = nullptr;
    La.Po[0] = nullptr; La.Po[1] = nullptr; La.Po[2] = nullptr;
    layer_kernel<2><<<dim3(256), dim3(256), 0, stream>>>(La);
  }

  // 6) head
  head_kernel<<<dim3(Bn), dim3(256), 0, stream>>>(
      hBpe, bn_graph_mean, bn_graph_var, bn_graph_gamma, bn_graph_beta, fc1_w,
      fc1_b, (float*)d_out);
}

// Round 12
// 68.271 us; speedup vs baseline: 2.7960x; 1.2612x over previous
//
#include <hip/hip_runtime.h>

typedef __attribute__((ext_vector_type(8))) short bf16x8;
typedef __attribute__((ext_vector_type(4))) float f32x4;
typedef __attribute__((ext_vector_type(8))) unsigned short u16x8;

constexpr int Bn = 16;
constexpr int Nn = 512;
constexpr int Fn = 64;
constexpr int Aout = 512;

static __device__ __forceinline__ unsigned short f2bf(float f) {
  union { float f; unsigned int u; } v; v.f = f;
  unsigned int r = v.u + 0x7fffu + ((v.u >> 16) & 1u);
  return (unsigned short)(r >> 16);
}
static __device__ __forceinline__ float bf2f(unsigned short u) {
  union { unsigned int u; float f; } v; v.u = ((unsigned int)u) << 16;
  return v.f;
}
static __device__ __forceinline__ unsigned int pk2(float a, float b) {
  union { float f; unsigned int u; } ua, ub; ua.f = a; ub.f = b;
  return ((ua.u + 0x8000u) >> 16) | ((ub.u + 0x8000u) & 0xFFFF0000u);
}
static __device__ __forceinline__ void gload_lds16(const float* g, float* l) {
  __builtin_amdgcn_global_load_lds(
      (const __attribute__((address_space(1))) void*)g,
      (__attribute__((address_space(3))) void*)l, 16, 0, 0);
}

// B-perm (X/B-operand fragment layout), cols c, contraction k, K total:
//   frag = (c>>4)*(K/32) + (k>>5); off = frag*512 + ((c&15) + 16*((k>>3)&3))*8 + (k&7)

// ---------------------------------------------------------------------------
// prep (weights only)
// ---------------------------------------------------------------------------
__launch_bounds__(256)
__global__ void prep_kernel(const float* __restrict__ Wi,
                            unsigned short* __restrict__ Wp,
                            const float* __restrict__ W0,
                            const float* __restrict__ W1,
                            const float* __restrict__ W2,
                            const float* __restrict__ W3,
                            unsigned short* __restrict__ Wall) {
  const int blk = blockIdx.x;
  if (blk < 16) {
    const int idx = blk * 256 + threadIdx.x;  // [0,4096)
    const int f = idx >> 6, o = idx & 63;
    const int k0 = o * 8;
    const size_t dst = ((size_t)((f >> 4) * 16 + (k0 >> 5)) << 9) +
                       (((f & 15) + 16 * ((k0 >> 3) & 3)) << 3);
    unsigned short w[8];
#pragma unroll
    for (int j = 0; j < 8; ++j) w[j] = f2bf(Wi[(size_t)(k0 + j) * Fn + f]);
    *(uint4*)(Wp + dst) = *(const uint4*)w;
  } else {
    const int r = blk - 16;
    const int mat = r >> 1;  // 0..11 = l*4 + m (m: W3,W0,W1,W2)
    const int l = mat >> 2, m = mat & 3;
    const int idx = (r & 1) * 256 + threadIdx.x;  // [0,512)
    const int co = idx >> 3, oct = idx & 7;
    const int k0 = oct * 8;
    const float* src = (m == 0 ? W3 : m == 1 ? W0 : m == 2 ? W1 : W2) + l * 4096;
    const size_t dst = (size_t)mat * 4096 +
                       ((size_t)((co >> 4) * 2 + (k0 >> 5)) << 9) +
                       (((co & 15) + 16 * ((k0 >> 3) & 3)) << 3);
    unsigned short w[8];
#pragma unroll
    for (int j = 0; j < 8; ++j) w[j] = f2bf(src[(k0 + j) * 64 + co]);
    *(uint4*)(Wall + dst) = *(const uint4*)w;
  }
}

// ---------------------------------------------------------------------------
// h0 kernel (32-row tiles, grid 256): h0 = relu(BN_init(hs @ Wi)).
// wave w: rows (w&1)*16, f-cols (w>>1)*32. Depth-2 reg prefetch.
// ---------------------------------------------------------------------------
__launch_bounds__(256, 1)
__global__ void h0_kernel(const float* __restrict__ hs,
                          const unsigned short* __restrict__ Wp,
                          const float* __restrict__ mean,
                          const float* __restrict__ var,
                          const float* __restrict__ gamma,
                          const float* __restrict__ beta,
                          unsigned short* __restrict__ operm,
                          unsigned short* __restrict__ olin) {
  const int b = blockIdx.y;
  const int R0 = blockIdx.x * 32;
  const int tid = threadIdx.x;
  const int w = tid >> 6, l = tid & 63;
  const int lr = l & 15, q = l >> 4;
  const int nsub = (w & 1) * 16;
  const int cstart = (w >> 1) * 2;

  const float* Af =
      hs + ((size_t)b << 18) + (size_t)(R0 + nsub + lr) * 512 + q * 8;
  const unsigned short* Xf = Wp + cstart * 8192 + l * 8;

  f32x4 acc[2] = {{0.f, 0.f, 0.f, 0.f}, {0.f, 0.f, 0.f, 0.f}};
  float4 ral[2][2];
  bf16x8 xb[2][2];
#define LD0(S_, T_)                                                       \
  {                                                                       \
    ral[S_][0] = *(const float4*)(Af + (T_)*32);                          \
    ral[S_][1] = *(const float4*)(Af + (T_)*32 + 4);                      \
    xb[S_][0] = *(const bf16x8*)(Xf + (T_)*512);                          \
    xb[S_][1] = *(const bf16x8*)(Xf + 8192 + (T_)*512);                   \
  }
  LD0(0, 0)
#pragma unroll
  for (int t = 0; t < 16; ++t) {
    const int cur = t & 1;
    if (t + 1 < 16) LD0(cur ^ 1, t + 1)
    union { bf16x8 v; unsigned int u[4]; } cv;
    cv.u[0] = pk2(ral[cur][0].x, ral[cur][0].y);
    cv.u[1] = pk2(ral[cur][0].z, ral[cur][0].w);
    cv.u[2] = pk2(ral[cur][1].x, ral[cur][1].y);
    cv.u[3] = pk2(ral[cur][1].z, ral[cur][1].w);
#pragma unroll
    for (int c = 0; c < 2; ++c)
      acc[c] = __builtin_amdgcn_mfma_f32_16x16x32_bf16(cv.v, xb[cur][c], acc[c], 0, 0, 0);
  }
#undef LD0

  __shared__ __align__(16) unsigned short Tfn[64][40];  // [f][n 32+pad]
  __shared__ __align__(16) unsigned short Tnf[32][72];  // [n][f]
  float sc[4], mu[4], bt[4];
#pragma unroll
  for (int i = 0; i < 4; ++i) {
    int n = R0 + nsub + q * 4 + i;
    sc[i] = rsqrtf(var[n] + 1e-5f) * gamma[n];
    mu[i] = mean[n];
    bt[i] = beta[n];
  }
#pragma unroll
  for (int c = 0; c < 2; ++c) {
    const int f = (cstart + c) * 16 + lr;
    ushort4 wv;
#pragma unroll
    for (int i = 0; i < 4; ++i) {
      float v = fmaxf(fmaf(acc[c][i] - mu[i], sc[i], bt[i]), 0.f);
      unsigned short uv = f2bf(v);
      ((unsigned short*)&wv)[i] = uv;
      Tnf[nsub + q * 4 + i][f] = uv;
    }
    *(ushort4*)&Tfn[f][nsub + q * 4] = wv;
  }
  __syncthreads();
  {
    // B-perm store: 64 f x 4 octets of n
    const int f = tid >> 2, oc = tid & 3;
    const int n = R0 + oc * 8;
    const size_t dst = ((size_t)b << 15) +
                       ((size_t)((f >> 4) * 16 + (n >> 5)) << 9) +
                       (((f & 15) + 16 * ((n >> 3) & 3)) << 3);
    *(uint4*)(operm + dst) = *(const uint4*)&Tfn[f][oc * 8];
    // linear store: 32 n x 64 f
    const int nl = tid >> 3, oc8 = tid & 7;
    *(uint4*)(olin + ((size_t)b << 15) + (size_t)(R0 + nl) * 64 + oc8 * 8) =
        *(const uint4*)&Tnf[nl][oc8 * 8];
  }
}

// ---------------------------------------------------------------------------
// layer kernel (v12): 16-row tiles, grid 512 (2 blocks/CU), BK=64 (8 steps).
//  phase A: P_z = a_z@h (+ asum@P_z_old); fp32 adjacency staged LDS-direct
//  (waves 0..2 stage z=w; XOR-preswizzled source); X depth-2 VGPR prefetch.
//  phase B: h_tmp = h@W3 + sum_z P_z@W_z -> bias+BN+ReLU -> h_next.
// ---------------------------------------------------------------------------
struct LArgs {
  const float* Af0;
  const float* Af1;
  const float* Af2;
  const unsigned short* Xh;
  const unsigned short* XP[3];
  const unsigned short* hlin;
  const unsigned short* Wl;
  const float *bias, *mean, *var, *gamma, *beta;
  unsigned short* hperm_o;
  unsigned short* hlin_o;
  unsigned short* Po[3];
};

template <int NSEG>
__launch_bounds__(256, 2)
__global__ void layer_kernel(LArgs La) {
  const int flat = blockIdx.x;  // 512; flat&7 = XCD; all tiles of b on one XCD
  const int b = (flat & 7) + 8 * ((flat >> 3) & 1);
  const int R0 = (flat >> 4) * 16;
  const int tid = threadIdx.x;
  const int w = tid >> 6, l = tid & 63;
  const int lr = l & 15, q = l >> 4;

  __shared__ __align__(16) float Asg[2][3][16][64];        // 24 KB
  __shared__ __align__(16) unsigned short Tnf[3][16][72];  // [z][n][f]
  __shared__ __align__(16) unsigned short Tfn[3][64][24];  // [z][f][n]
  __shared__ __align__(16) unsigned short Hfn[64][24];
  __shared__ __align__(16) unsigned short Hnf[16][72];

  // staging: wave z=w (w<3) stages its adjacency tile; 4 calls of 4 rows.
  const float* Az = (w == 0) ? La.Af0 : (w == 1) ? La.Af1 : La.Af2;
  const float* Abase = Az + ((size_t)b << 18) + (size_t)R0 * 512;
  size_t aoff[4];
#pragma unroll
  for (int c = 0; c < 4; ++c) {
    const int arow = c * 4 + (l >> 4);
    const int agc = (l & 15) ^ arow;  // slot chunk l&15 holds global chunk agc
    aoff[c] = (size_t)arow * 512 + agc * 4;
  }

  const size_t xoff = ((size_t)b << 15) + (size_t)w * 8192 + l * 8;
  const unsigned short* Xhp = La.Xh + xoff;
  const unsigned short* XP0p = (NSEG == 2) ? La.XP[0] + xoff : Xhp;
  const unsigned short* XP1p = (NSEG == 2) ? La.XP[1] + xoff : Xhp;
  const unsigned short* XP2p = (NSEG == 2) ? La.XP[2] + xoff : Xhp;

  f32x4 acc[3] = {{0.f, 0.f, 0.f, 0.f},
                  {0.f, 0.f, 0.f, 0.f},
                  {0.f, 0.f, 0.f, 0.f}};
  bf16x8 rxh[2][2];
  bf16x8 rxp[2][3][2];

#define STAGE(BB, T)                                                     \
  if (w < 3) {                                                           \
    _Pragma("unroll") for (int c = 0; c < 4; ++c)                        \
        gload_lds16(Abase + aoff[c] + (T)*64, &Asg[BB][w][c * 4][0]);    \
  }
#define LOADX(S_, T_)                                                    \
  {                                                                      \
    rxh[S_][0] = *(const bf16x8*)(Xhp + (2 * (T_)) * 512);               \
    rxh[S_][1] = *(const bf16x8*)(Xhp + (2 * (T_) + 1) * 512);           \
    if (NSEG == 2) {                                                     \
      rxp[S_][0][0] = *(const bf16x8*)(XP0p + (2 * (T_)) * 512);         \
      rxp[S_][0][1] = *(const bf16x8*)(XP0p + (2 * (T_) + 1) * 512);     \
      rxp[S_][1][0] = *(const bf16x8*)(XP1p + (2 * (T_)) * 512);         \
      rxp[S_][1][1] = *(const bf16x8*)(XP1p + (2 * (T_) + 1) * 512);     \
      rxp[S_][2][0] = *(const bf16x8*)(XP2p + (2 * (T_)) * 512);         \
      rxp[S_][2][1] = *(const bf16x8*)(XP2p + (2 * (T_) + 1) * 512);     \
    }                                                                    \
  }

  STAGE(0, 0)
  LOADX(0, 0)
  __syncthreads();

#pragma unroll
  for (int t = 0; t < 8; ++t) {
    const int cur = t & 1;
    if (t + 1 < 8) {
      STAGE(cur ^ 1, t + 1)
      LOADX(cur ^ 1, t + 1)
    }
#pragma unroll
    for (int kf = 0; kf < 2; ++kf) {
      float4 fa[3], fb[3];
#pragma unroll
      for (int z = 0; z < 3; ++z) {
        fa[z] = *(const float4*)&Asg[cur][z][lr][((kf * 8 + 2 * q) ^ lr) << 2];
        fb[z] = *(const float4*)&Asg[cur][z][lr][((kf * 8 + 2 * q + 1) ^ lr) << 2];
      }
      bf16x8 azf[3];
#pragma unroll
      for (int z = 0; z < 3; ++z) {
        union { bf16x8 v; unsigned int u[4]; } cv;
        cv.u[0] = pk2(fa[z].x, fa[z].y);
        cv.u[1] = pk2(fa[z].z, fa[z].w);
        cv.u[2] = pk2(fb[z].x, fb[z].y);
        cv.u[3] = pk2(fb[z].z, fb[z].w);
        azf[z] = cv.v;
      }
      bf16x8 asumf;
      if (NSEG == 2) {
        union { bf16x8 v; unsigned int u[4]; } cv;
        cv.u[0] = pk2(fa[0].x + fa[1].x + fa[2].x, fa[0].y + fa[1].y + fa[2].y);
        cv.u[1] = pk2(fa[0].z + fa[1].z + fa[2].z, fa[0].w + fa[1].w + fa[2].w);
        cv.u[2] = pk2(fb[0].x + fb[1].x + fb[2].x, fb[0].y + fb[1].y + fb[2].y);
        cv.u[3] = pk2(fb[0].z + fb[1].z + fb[2].z, fb[0].w + fb[1].w + fb[2].w);
        asumf = cv.v;
      }
#pragma unroll
      for (int z = 0; z < 3; ++z) {
        acc[z] = __builtin_amdgcn_mfma_f32_16x16x32_bf16(azf[z], rxh[cur][kf],
                                                         acc[z], 0, 0, 0);
        if (NSEG == 2)
          acc[z] = __builtin_amdgcn_mfma_f32_16x16x32_bf16(
              asumf, rxp[cur][z][kf], acc[z], 0, 0, 0);
      }
    }
    __syncthreads();
  }
#undef STAGE
#undef LOADX

  // stage P_z tiles to LDS (both layouts)
#pragma unroll
  for (int z = 0; z < 3; ++z) {
    const int f = w * 16 + lr;
    ushort4 wv;
#pragma unroll
    for (int i = 0; i < 4; ++i) {
      unsigned short uv = f2bf(acc[z][i]);
      ((unsigned short*)&wv)[i] = uv;
      Tnf[z][q * 4 + i][f] = uv;
    }
    *(ushort4*)&Tfn[z][f][q * 4] = wv;
  }
  __syncthreads();

  // P_z global stores (B-perm): 64 f x 2 octets
  if (La.Po[0] != nullptr && tid < 128) {
    const int f = tid >> 1, o = tid & 1;
    const int n = R0 + o * 8;
    const size_t dst = ((size_t)b << 15) +
                       ((size_t)((f >> 4) * 16 + (n >> 5)) << 9) +
                       (((f & 15) + 16 * ((n >> 3) & 3)) << 3);
#pragma unroll
    for (int z = 0; z < 3; ++z)
      *(uint4*)(La.Po[z] + dst) = *(const uint4*)&Tfn[z][f][o * 8];
  }

  // phase B: h_tmp = h@W3 + sum_z P_z@W_z (contraction over f'=64)
  f32x4 acch = {0.f, 0.f, 0.f, 0.f};
#pragma unroll
  for (int m = 0; m < 4; ++m) {
#pragma unroll
    for (int ks = 0; ks < 2; ++ks) {
      bf16x8 af;
      if (m == 0)
        af = *(const bf16x8*)(La.hlin + ((size_t)b << 15) +
                              (size_t)(R0 + lr) * 64 + q * 8 + ks * 32);
      else
        af = *(const bf16x8*)&Tnf[m - 1][lr][q * 8 + ks * 32];
      const bf16x8 bf_ = *(const bf16x8*)(La.Wl + m * 4096 +
                                          ((size_t)(w * 2 + ks) << 9) + l * 8);
      acch = __builtin_amdgcn_mfma_f32_16x16x32_bf16(af, bf_, acch, 0, 0, 0);
    }
  }

  // epilogue: bias + BN + ReLU -> Hfn/Hnf
  {
    float sc[4], mu[4], bt[4];
#pragma unroll
    for (int i = 0; i < 4; ++i) {
      int n = R0 + q * 4 + i;
      sc[i] = rsqrtf(La.var[n] + 1e-5f) * La.gamma[n];
      mu[i] = La.mean[n];
      bt[i] = La.beta[n];
    }
    const int f = w * 16 + lr;
    const float bia = La.bias[f];
    ushort4 wv;
#pragma unroll
    for (int i = 0; i < 4; ++i) {
      float v = acch[i] + bia;
      v = fmaxf(fmaf(v - mu[i], sc[i], bt[i]), 0.f);
      unsigned short uv = f2bf(v);
      ((unsigned short*)&wv)[i] = uv;
      Hnf[q * 4 + i][f] = uv;
    }
    *(ushort4*)&Hfn[f][q * 4] = wv;
  }
  __syncthreads();

  // h_next global stores
  if (tid < 128) {
    const int f = tid >> 1, o = tid & 1;
    const int n = R0 + o * 8;
    const size_t dst = ((size_t)b << 15) +
                       ((size_t)((f >> 4) * 16 + (n >> 5)) << 9) +
                       (((f & 15) + 16 * ((n >> 3) & 3)) << 3);
    *(uint4*)(La.hperm_o + dst) = *(const uint4*)&Hfn[f][o * 8];
    if (La.hlin_o != nullptr) {
      const int nl = tid >> 3, oc8 = tid & 7;  // 16 n x 8 chunks
      *(uint4*)(La.hlin_o + ((size_t)b << 15) + (size_t)(R0 + nl) * 64 +
                oc8 * 8) = *(const uint4*)&Hnf[nl][oc8 * 8];
    }
  }
}

// ---------------------------------------------------------------------------
// head: sum over n (B-perm h3) -> BN+ReLU -> FC(512) -> softmax. block per b.
// ---------------------------------------------------------------------------
__launch_bounds__(256)
__global__ void head_kernel(const unsigned short* __restrict__ h3p,
                            const float* __restrict__ gmean,
                            const float* __restrict__ gvar,
                            const float* __restrict__ ggamma,
                            const float* __restrict__ gbeta,
                            const float* __restrict__ fc_w,
                            const float* __restrict__ fc_b,
                            float* __restrict__ out) {
  const int b = blockIdx.x;
  const int t = threadIdx.x;
  __shared__ float part[256];
  __shared__ float gh[64];
  __shared__ float red[256];

  const int f = t >> 2, q = t & 3;
  const unsigned short* hp = h3p + ((size_t)b << 15);
  float s = 0.f;
#pragma unroll
  for (int m = 0; m < 16; ++m) {
    const int n = q * 128 + m * 8;
    const size_t off = ((size_t)((f >> 4) * 16 + (n >> 5)) << 9) +
                       (((f & 15) + 16 * ((n >> 3) & 3)) << 3);
    u16x8 v = *(const u16x8*)(hp + off);
#pragma unroll
    for (int e = 0; e < 8; ++e) s += bf2f((unsigned short)v[e]);
  }
  part[t] = s;
  __syncthreads();
  if (t < 64) {
    float sum = part[t * 4] + part[t * 4 + 1] + part[t * 4 + 2] + part[t * 4 + 3];
    float sc = rsqrtf(gvar[t] + 1e-5f) * ggamma[t];
    float v = fmaf(sum - gmean[t], sc, gbeta[t]);
    gh[t] = v > 0.f ? v : 0.f;
  }
  __syncthreads();

  float lg[2];
#pragma unroll
  for (int rep = 0; rep < 2; ++rep) {
    const int a = t + rep * 256;
    const float* __restrict__ wv = fc_w + (size_t)a * Fn;
    float acc = fc_b[a];
#pragma unroll 8
    for (int kk = 0; kk < 64; ++kk) acc = fmaf(gh[kk], wv[kk], acc);
    lg[rep] = acc;
  }
  red[t] = fmaxf(lg[0], lg[1]);
  __syncthreads();
  for (int off = 128; off > 0; off >>= 1) {
    if (t < off) red[t] = fmaxf(red[t], red[t + off]);
    __syncthreads();
  }
  const float mx = red[0];
  __syncthreads();
  const float e0 = __expf(lg[0] - mx), e1 = __expf(lg[1] - mx);
  red[t] = e0 + e1;
  __syncthreads();
  for (int off = 128; off > 0; off >>= 1) {
    if (t < off) red[t] += red[t + off];
    __syncthreads();
  }
  const float inv = 1.f / red[0];
  out[(size_t)b * Aout + t] = e0 * inv;
  out[(size_t)b * Aout + t + 256] = e1 * inv;
}

// ---------------------------------------------------------------------------
extern "C" void kernel_launch(void* const* d_in, const int* in_sizes, int n_in,
                              void* d_out, int out_size, void* d_ws,
                              size_t ws_size, hipStream_t stream) {
  (void)in_sizes; (void)n_in; (void)out_size; (void)ws_size;
  const float* hs_init = (const float*)d_in[0];
  const float* adjs0 = (const float*)d_in[1];
  const float* adjs1 = (const float*)d_in[2];
  const float* adjs2 = (const float*)d_in[3];
  const float* W_init = (const float*)d_in[4];
  const float* W0 = (const float*)d_in[5];
  const float* W1 = (const float*)d_in[6];
  const float* W2 = (const float*)d_in[7];
  const float* W3 = (const float*)d_in[8];
  const float* bvec = (const float*)d_in[9];
  const float* fc1_w = (const float*)d_in[10];
  const float* fc1_b = (const float*)d_in[11];
  const float* bn_init_mean = (const float*)d_in[12];
  const float* bn_init_var = (const float*)d_in[13];
  const float* bn_init_gamma = (const float*)d_in[14];
  const float* bn_init_beta = (const float*)d_in[15];
  const float* bn_layer_mean = (const float*)d_in[16];
  const float* bn_layer_var = (const float*)d_in[17];
  const float* bn_layer_gamma = (const float*)d_in[18];
  const float* bn_layer_beta = (const float*)d_in[19];
  const float* bn_graph_mean = (const float*)d_in[20];
  const float* bn_graph_var = (const float*)d_in[21];
  const float* bn_graph_gamma = (const float*)d_in[22];
  const float* bn_graph_beta = (const float*)d_in[23];

  const size_t NF = (size_t)Bn * Fn * Nn;  // 524,288

  unsigned short* wsu = (unsigned short*)d_ws;
  unsigned short* Wp = wsu;            // 32768
  unsigned short* Wall = Wp + 32768;   // 49152
  unsigned short* hApe = Wall + 49152;
  unsigned short* hBpe = hApe + NF;
  unsigned short* hAli = hBpe + NF;
  unsigned short* hBli = hAli + NF;
  unsigned short* PA0 = hBli + NF;
  unsigned short* PA1 = PA0 + NF;
  unsigned short* PA2 = PA1 + NF;
  unsigned short* PB0 = PA2 + NF;
  unsigned short* PB1 = PB0 + NF;
  unsigned short* PB2 = PB1 + NF;

  prep_kernel<<<dim3(40), dim3(256), 0, stream>>>(W_init, Wp, W0, W1, W2, W3,
                                                  Wall);

  h0_kernel<<<dim3(16, Bn), dim3(256), 0, stream>>>(
      hs_init, Wp, bn_init_mean, bn_init_var, bn_init_gamma, bn_init_beta,
      hApe, hAli);

  // L0
  {
    LArgs La = {};
    La.Af0 = adjs0; La.Af1 = adjs1; La.Af2 = adjs2;
    La.Xh = hApe; La.hlin = hAli;
    La.Wl = Wall;
    La.bias = bvec; La.mean = bn_layer_mean; La.var = bn_layer_var;
    La.gamma = bn_layer_gamma; La.beta = bn_layer_beta;
    La.hperm_o = hBpe; La.hlin_o = hBli;
    La.Po[0] = PA0; La.Po[1] = PA1; La.Po[2] = PA2;
    layer_kernel<1><<<dim3(512), dim3(256), 0, stream>>>(La);
  }
  // L1
  {
    LArgs La = {};
    La.Af0 = adjs0; La.Af1 = adjs1; La.Af2 = adjs2;
    La.Xh = hBpe; La.hlin = hBli;
    La.XP[0] = PA0; La.XP[1] = PA1; La.XP[2] = PA2;
    La.Wl = Wall + 4 * 4096;
    La.bias = bvec + 64; La.mean = bn_layer_mean + 512;
    La.var = bn_layer_var + 512; La.gamma = bn_layer_gamma + 512;
    La.beta = bn_layer_beta + 512;
    La.hperm_o = hApe; La.hlin_o = hAli;
    La.Po[0] = PB0; La.Po[1] = PB1; La.Po[2] = PB2;
    layer_kernel<2><<<dim3(512), dim3(256), 0, stream>>>(La);
  }
  // L2
  {
    LArgs La = {};
    La.Af0 = adjs0; La.Af1 = adjs1; La.Af2 = adjs2;
    La.Xh = hApe; La.hlin = hAli;
    La.XP[0] = PB0; La.XP[1] = PB1; La.XP[2] = PB2;
    La.Wl = Wall + 8 * 4096;
    La.bias = bvec + 128; La.mean = bn_layer_mean + 1024;
    La.var = bn_layer_var + 1024; La.gamma = bn_layer_gamma + 1024;
    La.beta = bn_layer_beta + 1024;
    La.hperm_o = hBpe; La.hlin_o = nullptr;
    La.Po[0] = nullptr; La.Po[1] = nullptr; La.Po[2] = nullptr;
    layer_kernel<2><<<dim3(512), dim3(256), 0, stream>>>(La);
  }

  head_kernel<<<dim3(Bn), dim3(256), 0, stream>>>(
      hBpe, bn_graph_mean, bn_graph_var, bn_graph_gamma, bn_graph_beta, fc1_w,
      fc1_b, (float*)d_out);
}